// Round 6
// baseline (335.967 us; speedup 1.0000x reference)
//
#include <hip/hip_runtime.h>

// InteractionBlock: N=10000, E=320000, C=64, A=4, NB=8, H=8.
// Pipeline:
//   k_pack     : bf16-pair pack of (W10,W11),(Ws0,Ws1),(W20 row-pairs),(W21 row-pairs)
//   memset cnt -> k_hist -> k_scan (2-barrier shuffle scan)
//   k_build    : CSR scatter + edge MLP; writes ehh[p]=uint4(bf16 h[8]), esh[p]=f32 sh
//   k_node_pre : 8 nodes/block; yqb[n][u]=ushort4 bf16{y0,y1m}; sc (f32) -> out
//   k_agg      : one node per WAVE, no barriers; Wf2 in regs; bf16 gather;
//                writes bf16 agg[n][512]
//   k_lin2     : 16 nodes/block (4/wave), agg unpacked to LDS f32, packed weights

__device__ __forceinline__ unsigned short f2b(float f) {
  unsigned u = __float_as_uint(f);
  return (unsigned short)((u + 0x7FFFu + ((u >> 16) & 1u)) >> 16);  // RNE
}
__device__ __forceinline__ unsigned packb(float a, float b) {
  return (unsigned)f2b(a) | ((unsigned)f2b(b) << 16);
}
__device__ __forceinline__ float blo(unsigned p) { return __uint_as_float(p << 16); }
__device__ __forceinline__ float bhi(unsigned p) { return __uint_as_float(p & 0xFFFF0000u); }
__device__ __forceinline__ float b2f(unsigned short h) {
  return __uint_as_float((unsigned)h << 16);
}

__global__ __launch_bounds__(256) void k_pack(
    const float* __restrict__ W10, const float* __restrict__ W11,
    const float* __restrict__ Ws0, const float* __restrict__ Ws1,
    const float* __restrict__ W20, const float* __restrict__ W21,
    unsigned* __restrict__ wpk1, unsigned* __restrict__ wpks,
    unsigned* __restrict__ wpk2a, unsigned* __restrict__ wpk2b) {
  int i = blockIdx.x * 256 + threadIdx.x;
  if (i < 4096) wpk1[i] = packb(W10[i], W11[i]);
  else if (i < 4096 + 16384) {
    int j = i - 4096;
    wpks[j] = packb(Ws0[j], Ws1[j]);
  } else if (i < 4096 + 16384 + 4096) {
    int j = i - (4096 + 16384);  // j = up*64+v, up<64
    wpk2a[j] = packb(W20[j], W20[4096 + j]);
  } else if (i < 4096 + 16384 + 8192) {
    int j = i - (4096 + 16384 + 4096);
    wpk2b[j] = packb(W21[j], W21[4096 + j]);
  }
}

__global__ __launch_bounds__(256) void k_hist(const int* __restrict__ ei,
                                              int* __restrict__ cnt, int nedges) {
  int e = blockIdx.x * 256 + threadIdx.x;
  if (e < nedges) atomicAdd(&cnt[ei[e]], 1);  // row 0 = dst
}

__global__ __launch_bounds__(1024) void k_scan(const int* __restrict__ cnt,
                                               int* __restrict__ offs,
                                               int* __restrict__ cur,
                                               int nnodes, int nedges) {
  __shared__ int s_wtot[16], s_wpre[16];
  const int tid = threadIdx.x;
  const int lane = tid & 63;
  const int w = tid >> 6;
  int vals[16];
  int tot = 0;
  const int start = tid * 16;
#pragma unroll
  for (int k = 0; k < 16; ++k) {
    int i = start + k;
    int c = (i < nnodes) ? cnt[i] : 0;
    vals[k] = c;
    tot += c;
  }
  int incl = tot;
#pragma unroll
  for (int off = 1; off < 64; off <<= 1) {
    int v = __shfl_up(incl, off, 64);
    if (lane >= off) incl += v;
  }
  if (lane == 63) s_wtot[w] = incl;
  __syncthreads();
  if (tid == 0) {
    int run = 0;
#pragma unroll
    for (int i = 0; i < 16; ++i) { s_wpre[i] = run; run += s_wtot[i]; }
  }
  __syncthreads();
  int run = s_wpre[w] + (incl - tot);
#pragma unroll
  for (int k = 0; k < 16; ++k) {
    int i = start + k;
    if (i < nnodes) {
      offs[i] = run;
      cur[i] = run;
      run += vals[k];
    }
  }
  if (tid == 0) offs[nnodes] = nedges;
}

// scatter + edge-MLP fused; bf16-packed h record.
__global__ __launch_bounds__(256) void k_build(
    const int* __restrict__ ei, const float* __restrict__ ee,
    const float* __restrict__ ea, const float* __restrict__ Wf1,
    int* __restrict__ cur, int* __restrict__ srcs,
    uint4* __restrict__ ehh, float4* __restrict__ esh, int nedges) {
  __shared__ float s_w[64];
  const int tid = threadIdx.x;
  if (tid < 64) s_w[tid] = Wf1[tid];
  __syncthreads();
  int e = blockIdx.x * 256 + tid;
  if (e >= nedges) return;
  const int d = ei[e];
  const int s = ei[nedges + e];
  const int p = atomicAdd(&cur[d], 1);
  srcs[p] = s;
  const float4 a = *(const float4*)(ee + (size_t)e * 8);
  const float4 b = *(const float4*)(ee + (size_t)e * 8 + 4);
  float r[8];
  const float is8 = 0.35355339059327379f;  // 1/sqrt(8)
#pragma unroll
  for (int j = 0; j < 8; ++j) {
    float dd = a.x * s_w[0 * 8 + j] + a.y * s_w[1 * 8 + j] + a.z * s_w[2 * 8 + j] +
               a.w * s_w[3 * 8 + j] + b.x * s_w[4 * 8 + j] + b.y * s_w[5 * 8 + j] +
               b.z * s_w[6 * 8 + j] + b.w * s_w[7 * 8 + j];
    dd *= is8;                                        // /sqrt(NB)
    float sp = fmaxf(dd, 0.f) + log1pf(__expf(-fabsf(dd)));
    r[j] = (sp - 0.69314718055994531f) * is8;         // -ln2, fold /sqrt(H)
  }
  ehh[p] = make_uint4(packb(r[0], r[1]), packb(r[2], r[3]),
                      packb(r[4], r[5]), packb(r[6], r[7]));
  esh[p] = *(const float4*)(ea + (size_t)e * 4);  // sh0, sh1
}

// 8 nodes per block (4 per wave, 2 waves), lane = output column v.
__global__ __launch_bounds__(128) void k_node_pre(
    const float* __restrict__ nf, const float* __restrict__ na,
    const unsigned* __restrict__ wpk1, const unsigned* __restrict__ wpks,
    unsigned short* __restrict__ yqb, float* __restrict__ out, int nnodes) {
  __shared__ float s_nf[8][256];
  __shared__ float s_na[8][4];
  const int tid = threadIdx.x;
  const int lane = tid & 63;
  const int wv = tid >> 6;
  const int base = blockIdx.x * 8;

  for (int i = tid; i < 8 * 256; i += 128) {
    int r = i >> 8, c = i & 255;
    int n = base + r;
    s_nf[r][c] = (n < nnodes) ? nf[(size_t)n * 256 + c] : 0.f;
  }
  if (tid < 32) {
    int r = tid >> 2, c = tid & 3;
    int n = base + r;
    s_na[r][c] = (n < nnodes) ? na[(size_t)n * 4 + c] : 0.f;
  }
  __syncthreads();

  const int r0 = wv * 4;
  const int v = lane;
  float y0a[4] = {0.f, 0.f, 0.f, 0.f};
  float y1a[4][3] = {};
  float sc0a[4] = {0.f, 0.f, 0.f, 0.f};
  float sc1a[4][3] = {};

#pragma unroll 4
  for (int u = 0; u < 64; ++u) {
    float x0r[4], x1r[4][3];
#pragma unroll
    for (int r = 0; r < 4; ++r) {
      x0r[r] = s_nf[r0 + r][u];
#pragma unroll
      for (int m = 0; m < 3; ++m) x1r[r][m] = s_nf[r0 + r][64 + u * 3 + m];
    }
    const unsigned q1 = wpk1[u * 64 + v];
    const float w0 = blo(q1);
    const float w1 = bhi(q1);
#pragma unroll
    for (int r = 0; r < 4; ++r) {
      y0a[r] = fmaf(x0r[r], w0, y0a[r]);
#pragma unroll
      for (int m = 0; m < 3; ++m) y1a[r][m] = fmaf(x1r[r][m], w1, y1a[r][m]);
    }
#pragma unroll
    for (int a = 0; a < 4; ++a) {
      const unsigned qs = wpks[(u * 4 + a) * 64 + v];
      const float ws0 = blo(qs);
      const float ws1 = bhi(qs);
#pragma unroll
      for (int r = 0; r < 4; ++r) {
        const float nav = s_na[r0 + r][a];
        sc0a[r] = fmaf(x0r[r] * nav, ws0, sc0a[r]);
        const float t = nav * ws1;
#pragma unroll
        for (int m = 0; m < 3; ++m)
          sc1a[r][m] = fmaf(x1r[r][m], t, sc1a[r][m]);
      }
    }
  }

#pragma unroll
  for (int r = 0; r < 4; ++r) {
    const int n = base + r0 + r;
    if (n < nnodes) {
      ushort4 yv;
      yv.x = f2b(y0a[r] * 0.125f);        // /sqrt(C)
      yv.y = f2b(y1a[r][0] * 0.125f);
      yv.z = f2b(y1a[r][1] * 0.125f);
      yv.w = f2b(y1a[r][2] * 0.125f);
      *(ushort4*)(yqb + ((size_t)n * 64 + v) * 4) = yv;
      out[(size_t)n * 256 + v] = sc0a[r] * 0.0625f;   // /sqrt(C*A)
#pragma unroll
      for (int m = 0; m < 3; ++m)
        out[(size_t)n * 256 + 64 + v * 3 + m] = sc1a[r][m] * 0.0625f;
    }
  }
}

// One node per WAVE; no barriers; bf16 gather; writes bf16 agg[n][512].
__global__ __launch_bounds__(256, 4) void k_agg(
    const unsigned short* __restrict__ yqb, const uint4* __restrict__ ehh,
    const float4* __restrict__ esh, const int* __restrict__ srcs,
    const int* __restrict__ offs, const float* __restrict__ Wf2,
    unsigned short* __restrict__ aggb, int nnodes) {
  const int tid = threadIdx.x;
  const int u = tid & 63;
  const int wv = tid >> 6;
  const int n = blockIdx.x * 4 + wv;
  if (n >= nnodes) return;

  float wreg[32];
#pragma unroll
  for (int j = 0; j < 8; ++j)
#pragma unroll
    for (int q = 0; q < 4; ++q) wreg[j * 4 + q] = Wf2[j * 256 + q * 64 + u];

  float as0 = 0.f, as1 = 0.f;
  float av0[3] = {0.f, 0.f, 0.f};
  float av1[3] = {0.f, 0.f, 0.f};

  const int beg = offs[n], end = offs[n + 1];
#pragma unroll 4
  for (int i = beg; i < end; ++i) {
    const int src = srcs[i];
    const ushort4 yb = *(const ushort4*)(yqb + ((size_t)src * 64 + u) * 4);
    const uint4 hp = ehh[i];
    const float4 sh = esh[i];
    const float hv[8] = {blo(hp.x), bhi(hp.x), blo(hp.y), bhi(hp.y),
                         blo(hp.z), bhi(hp.z), blo(hp.w), bhi(hp.w)};
    float wp[4] = {0.f, 0.f, 0.f, 0.f};
#pragma unroll
    for (int j = 0; j < 8; ++j)
#pragma unroll
      for (int q = 0; q < 4; ++q) wp[q] = fmaf(hv[j], wreg[j * 4 + q], wp[q]);
    const float y0 = b2f(yb.x), y1 = b2f(yb.y), y2 = b2f(yb.z), y3 = b2f(yb.w);
    const float dot3 = y1 * sh.y + y2 * sh.z + y3 * sh.w;
    as0 = fmaf(wp[0] * y0, sh.x, as0);
    as1 = fmaf(wp[3], dot3, as1);
    const float t2 = wp[1] * y0;
    av0[0] = fmaf(t2, sh.y, av0[0]);
    av0[1] = fmaf(t2, sh.z, av0[1]);
    av0[2] = fmaf(t2, sh.w, av0[2]);
    const float t3 = wp[2] * sh.x;
    av1[0] = fmaf(t3, y1, av1[0]);
    av1[1] = fmaf(t3, y2, av1[1]);
    av1[2] = fmaf(t3, y3, av1[2]);
  }

  unsigned short* ap = aggb + (size_t)n * 512;
  ap[u] = f2b(as0);
  ap[64 + u] = f2b(as1 * 0.57735026918962576f);  // /sqrt(3)
#pragma unroll
  for (int m = 0; m < 3; ++m) {
    ap[128 + m * 64 + u] = f2b(av0[m]);
    ap[320 + m * 64 + u] = f2b(av1[m]);
  }
}

// 16 nodes/block (4 per wave); bf16 agg unpacked into per-wave LDS f32 slice;
// packed row-pair weights; bounded unroll (anti-spill, round-3 lesson).
__global__ __launch_bounds__(256, 4) void k_lin2(
    const unsigned short* __restrict__ aggb, const unsigned* __restrict__ wpk2a,
    const unsigned* __restrict__ wpk2b, float* __restrict__ out, int nnodes) {
  __shared__ float s_x[4][4][512];  // 32 KB
  const int tid = threadIdx.x;
  const int u = tid & 63;
  const int wv = tid >> 6;
  const int nb = blockIdx.x * 16 + wv * 4;

#pragma unroll
  for (int r = 0; r < 4; ++r) {
    const int n = nb + r;
    if (n < nnodes) {
      const uint4 aw = *(const uint4*)(aggb + (size_t)n * 512 + u * 8);
      float4* dst = (float4*)&s_x[wv][r][u * 8];
      dst[0] = make_float4(blo(aw.x), bhi(aw.x), blo(aw.y), bhi(aw.y));
      dst[1] = make_float4(blo(aw.z), bhi(aw.z), blo(aw.w), bhi(aw.w));
    }
  }
  // per-wave private LDS slice: same-wave RAW only, no barrier needed.

  float o0[4] = {0.f, 0.f, 0.f, 0.f};
  float o1[4][3] = {};

#pragma unroll 2
  for (int up = 0; up < 64; ++up) {
    const unsigned qa = wpk2a[up * 64 + u];
    const unsigned qb = wpk2b[up * 64 + u];
    const float w20a = blo(qa), w20b = bhi(qa);
    const float w21a = blo(qb), w21b = bhi(qb);
#pragma unroll
    for (int r = 0; r < 4; ++r) {
      o0[r] = fmaf(s_x[wv][r][up], w20a, o0[r]);
      o0[r] = fmaf(s_x[wv][r][64 + up], w20b, o0[r]);
#pragma unroll
      for (int m = 0; m < 3; ++m) {
        o1[r][m] = fmaf(s_x[wv][r][128 + m * 64 + up], w21a, o1[r][m]);
        o1[r][m] = fmaf(s_x[wv][r][320 + m * 64 + up], w21b, o1[r][m]);
      }
    }
  }

  const float scl = 1.f / 64.f;  // 1/sqrt(32) * 1/sqrt(128)
#pragma unroll
  for (int r = 0; r < 4; ++r) {
    const int n = nb + r;
    if (n < nnodes) {
      out[(size_t)n * 256 + u] += o0[r] * scl;
#pragma unroll
      for (int m = 0; m < 3; ++m)
        out[(size_t)n * 256 + 64 + u * 3 + m] += o1[r][m] * scl;
    }
  }
}

extern "C" void kernel_launch(void* const* d_in, const int* in_sizes, int n_in,
                              void* d_out, int out_size, void* d_ws, size_t ws_size,
                              hipStream_t stream) {
  const float* nf = (const float*)d_in[0];
  const float* na = (const float*)d_in[1];
  const float* ea = (const float*)d_in[2];
  const float* ee = (const float*)d_in[3];
  const int* ei = (const int*)d_in[4];
  const float* W10 = (const float*)d_in[5];
  const float* W11 = (const float*)d_in[6];
  const float* Wf1 = (const float*)d_in[7];
  const float* Wf2 = (const float*)d_in[8];
  const float* W20 = (const float*)d_in[9];
  const float* W21 = (const float*)d_in[10];
  const float* Ws0 = (const float*)d_in[11];
  const float* Ws1 = (const float*)d_in[12];
  float* out = (float*)d_out;

  const int N = in_sizes[1] / 4;  // node_attrs is N x 4
  const int E = in_sizes[2] / 4;  // edge_attrs is E x 4

  char* w = (char*)d_ws;
  auto carve = [&](size_t bytes) {
    char* p = w;
    w += (bytes + 255) & ~(size_t)255;
    return p;
  };
  unsigned short* yqb = (unsigned short*)carve((size_t)N * 256 * 2);   // 5.12 MB
  uint4* ehh = (uint4*)carve((size_t)E * 16);                          // 5.12 MB
  float4* esh = (float4*)carve((size_t)E * 16);                        // 5.12 MB
  unsigned short* aggb = (unsigned short*)carve((size_t)N * 512 * 2);  // 10.24 MB
  unsigned* wpk1 = (unsigned*)carve(4096 * 4);
  unsigned* wpks = (unsigned*)carve(16384 * 4);
  unsigned* wpk2a = (unsigned*)carve(4096 * 4);
  unsigned* wpk2b = (unsigned*)carve(4096 * 4);
  int* cnt = (int*)carve((size_t)N * sizeof(int));
  int* offs = (int*)carve((size_t)(N + 1) * sizeof(int));
  int* cur = (int*)carve((size_t)N * sizeof(int));
  int* srcs = (int*)carve((size_t)E * sizeof(int));                    // 1.28 MB

  hipMemsetAsync(cnt, 0, (size_t)N * sizeof(int), stream);
  k_pack<<<(4096 + 16384 + 8192 + 255) / 256, 256, 0, stream>>>(
      W10, W11, Ws0, Ws1, W20, W21, wpk1, wpks, wpk2a, wpk2b);
  const int egrid = (E + 255) / 256;
  k_hist<<<egrid, 256, 0, stream>>>(ei, cnt, E);
  k_scan<<<1, 1024, 0, stream>>>(cnt, offs, cur, N, E);
  k_build<<<egrid, 256, 0, stream>>>(ei, ee, ea, Wf1, cur, srcs, ehh, esh, E);
  k_node_pre<<<(N + 7) / 8, 128, 0, stream>>>(nf, na, wpk1, wpks, yqb, out, N);
  k_agg<<<(N + 3) / 4, 256, 0, stream>>>(yqb, ehh, esh, srcs, offs, Wf2, aggb, N);
  k_lin2<<<(N + 15) / 16, 256, 0, stream>>>(aggb, wpk2a, wpk2b, out, N);
}

// Round 8
// 311.421 us; speedup vs baseline: 1.0788x; 1.0788x over previous
//
#include <hip/hip_runtime.h>

// InteractionBlock: N=10000, E=320000, C=64, A=4, NB=8, H=8.
// Pipeline:
//   k_pack     : bf16-pair pack of (W10,W11),(Ws0,Ws1),(W20 row-pairs),(W21 row-pairs)
//   memset cnt -> k_hist -> k_scan (2-barrier shuffle scan)
//   k_build    : CSR scatter + edge MLP; writes erec[p] = {uint4 bf16 h[8], f32 sh[4]}
//                as one interleaved 32B record
//   k_node_pre : weights resident in LDS (80KB, staged once/block); grid-stride over
//                16-node groups; yqb[n][u]=ushort4 bf16{y0,y1m}; sc (f32) -> out
//   k_agg      : one node per WAVE, no barriers; Wf2 in regs; bf16 gather;
//                writes bf16 agg[n][512]
//   k_lin2     : 16 nodes/block (4/wave), agg unpacked to LDS f32, packed weights

__device__ __forceinline__ unsigned short f2b(float f) {
  unsigned u = __float_as_uint(f);
  return (unsigned short)((u + 0x7FFFu + ((u >> 16) & 1u)) >> 16);  // RNE
}
__device__ __forceinline__ unsigned packb(float a, float b) {
  return (unsigned)f2b(a) | ((unsigned)f2b(b) << 16);
}
__device__ __forceinline__ float blo(unsigned p) { return __uint_as_float(p << 16); }
__device__ __forceinline__ float bhi(unsigned p) { return __uint_as_float(p & 0xFFFF0000u); }
__device__ __forceinline__ float b2f(unsigned short h) {
  return __uint_as_float((unsigned)h << 16);
}

__global__ __launch_bounds__(256) void k_pack(
    const float* __restrict__ W10, const float* __restrict__ W11,
    const float* __restrict__ Ws0, const float* __restrict__ Ws1,
    const float* __restrict__ W20, const float* __restrict__ W21,
    unsigned* __restrict__ wpk1, unsigned* __restrict__ wpks,
    unsigned* __restrict__ wpk2a, unsigned* __restrict__ wpk2b) {
  int i = blockIdx.x * 256 + threadIdx.x;
  if (i < 4096) wpk1[i] = packb(W10[i], W11[i]);
  else if (i < 4096 + 16384) {
    int j = i - 4096;
    wpks[j] = packb(Ws0[j], Ws1[j]);
  } else if (i < 4096 + 16384 + 4096) {
    int j = i - (4096 + 16384);  // j = up*64+v, up<64
    wpk2a[j] = packb(W20[j], W20[4096 + j]);
  } else if (i < 4096 + 16384 + 8192) {
    int j = i - (4096 + 16384 + 4096);
    wpk2b[j] = packb(W21[j], W21[4096 + j]);
  }
}

__global__ __launch_bounds__(256) void k_hist(const int* __restrict__ ei,
                                              int* __restrict__ cnt, int nedges) {
  int e = blockIdx.x * 256 + threadIdx.x;
  if (e < nedges) atomicAdd(&cnt[ei[e]], 1);  // row 0 = dst
}

__global__ __launch_bounds__(1024) void k_scan(const int* __restrict__ cnt,
                                               int* __restrict__ offs,
                                               int* __restrict__ cur,
                                               int nnodes, int nedges) {
  __shared__ int s_wtot[16], s_wpre[16];
  const int tid = threadIdx.x;
  const int lane = tid & 63;
  const int w = tid >> 6;
  int vals[16];
  int tot = 0;
  const int start = tid * 16;
#pragma unroll
  for (int k = 0; k < 16; ++k) {
    int i = start + k;
    int c = (i < nnodes) ? cnt[i] : 0;
    vals[k] = c;
    tot += c;
  }
  int incl = tot;
#pragma unroll
  for (int off = 1; off < 64; off <<= 1) {
    int v = __shfl_up(incl, off, 64);
    if (lane >= off) incl += v;
  }
  if (lane == 63) s_wtot[w] = incl;
  __syncthreads();
  if (tid == 0) {
    int run = 0;
#pragma unroll
    for (int i = 0; i < 16; ++i) { s_wpre[i] = run; run += s_wtot[i]; }
  }
  __syncthreads();
  int run = s_wpre[w] + (incl - tot);
#pragma unroll
  for (int k = 0; k < 16; ++k) {
    int i = start + k;
    if (i < nnodes) {
      offs[i] = run;
      cur[i] = run;
      run += vals[k];
    }
  }
  if (tid == 0) offs[nnodes] = nedges;
}

// scatter + edge-MLP fused; one interleaved 32B record per edge.
__global__ __launch_bounds__(256) void k_build(
    const int* __restrict__ ei, const float* __restrict__ ee,
    const float* __restrict__ ea, const float* __restrict__ Wf1,
    int* __restrict__ cur, int* __restrict__ srcs,
    uint4* __restrict__ erec, int nedges) {
  __shared__ float s_w[64];
  const int tid = threadIdx.x;
  if (tid < 64) s_w[tid] = Wf1[tid];
  __syncthreads();
  int e = blockIdx.x * 256 + tid;
  if (e >= nedges) return;
  const int d = ei[e];
  const int s = ei[nedges + e];
  const int p = atomicAdd(&cur[d], 1);
  srcs[p] = s;
  const float4 a = *(const float4*)(ee + (size_t)e * 8);
  const float4 b = *(const float4*)(ee + (size_t)e * 8 + 4);
  float r[8];
  const float is8 = 0.35355339059327379f;  // 1/sqrt(8)
#pragma unroll
  for (int j = 0; j < 8; ++j) {
    float dd = a.x * s_w[0 * 8 + j] + a.y * s_w[1 * 8 + j] + a.z * s_w[2 * 8 + j] +
               a.w * s_w[3 * 8 + j] + b.x * s_w[4 * 8 + j] + b.y * s_w[5 * 8 + j] +
               b.z * s_w[6 * 8 + j] + b.w * s_w[7 * 8 + j];
    dd *= is8;                                        // /sqrt(NB)
    float sp = fmaxf(dd, 0.f) + log1pf(__expf(-fabsf(dd)));
    r[j] = (sp - 0.69314718055994531f) * is8;         // -ln2, fold /sqrt(H)
  }
  const float4 sh = *(const float4*)(ea + (size_t)e * 4);  // sh0, sh1
  erec[(size_t)p * 2] = make_uint4(packb(r[0], r[1]), packb(r[2], r[3]),
                                   packb(r[4], r[5]), packb(r[6], r[7]));
  erec[(size_t)p * 2 + 1] =
      make_uint4(__float_as_uint(sh.x), __float_as_uint(sh.y),
                 __float_as_uint(sh.z), __float_as_uint(sh.w));
}

// Weights resident in LDS (80KB); grid-stride over 16-node groups;
// 256 threads = 4 waves, 4 nodes per wave per group; lane = output column v.
__global__ __launch_bounds__(256) void k_node_pre(
    const float* __restrict__ nf, const float* __restrict__ na,
    const unsigned* __restrict__ wpk1, const unsigned* __restrict__ wpks,
    unsigned short* __restrict__ yqb, float* __restrict__ out, int nnodes) {
  __shared__ unsigned s_w1[4096];   // 16 KB: (W10,W11) packed, [u*64+v]
  __shared__ unsigned s_ws[16384];  // 64 KB: (Ws0,Ws1) packed, [(u*4+a)*64+v]
  __shared__ float s_nf[16][256];   // 16 KB
  __shared__ float s_na[16][4];
  const int tid = threadIdx.x;
  const int lane = tid & 63;
  const int wv = tid >> 6;

  for (int i = tid; i < 4096; i += 256) s_w1[i] = wpk1[i];
  for (int i = tid; i < 16384; i += 256) s_ws[i] = wpks[i];

  const int ngroups = (nnodes + 15) / 16;
  for (int g = blockIdx.x; g < ngroups; g += gridDim.x) {
    const int base = g * 16;
    __syncthreads();  // weight staging (first iter) + s_nf reuse (later iters)
    for (int i = tid; i < 16 * 256; i += 256) {
      int r = i >> 8, c = i & 255;
      int n = base + r;
      s_nf[r][c] = (n < nnodes) ? nf[(size_t)n * 256 + c] : 0.f;
    }
    if (tid < 64) {
      int r = tid >> 2, c = tid & 3;
      int n = base + r;
      s_na[r][c] = (n < nnodes) ? na[(size_t)n * 4 + c] : 0.f;
    }
    __syncthreads();

    const int r0 = wv * 4;
    const int v = lane;
    float y0a[4] = {0.f, 0.f, 0.f, 0.f};
    float y1a[4][3] = {};
    float sc0a[4] = {0.f, 0.f, 0.f, 0.f};
    float sc1a[4][3] = {};

#pragma unroll 4
    for (int u = 0; u < 64; ++u) {
      float x0r[4], x1r[4][3];
#pragma unroll
      for (int r = 0; r < 4; ++r) {
        x0r[r] = s_nf[r0 + r][u];
#pragma unroll
        for (int m = 0; m < 3; ++m) x1r[r][m] = s_nf[r0 + r][64 + u * 3 + m];
      }
      const unsigned q1 = s_w1[u * 64 + v];
      const float w0 = blo(q1);
      const float w1 = bhi(q1);
#pragma unroll
      for (int r = 0; r < 4; ++r) {
        y0a[r] = fmaf(x0r[r], w0, y0a[r]);
#pragma unroll
        for (int m = 0; m < 3; ++m) y1a[r][m] = fmaf(x1r[r][m], w1, y1a[r][m]);
      }
#pragma unroll
      for (int a = 0; a < 4; ++a) {
        const unsigned qs = s_ws[(u * 4 + a) * 64 + v];
        const float ws0 = blo(qs);
        const float ws1 = bhi(qs);
#pragma unroll
        for (int r = 0; r < 4; ++r) {
          const float nav = s_na[r0 + r][a];
          sc0a[r] = fmaf(x0r[r] * nav, ws0, sc0a[r]);
          const float t = nav * ws1;
#pragma unroll
          for (int m = 0; m < 3; ++m)
            sc1a[r][m] = fmaf(x1r[r][m], t, sc1a[r][m]);
        }
      }
    }

#pragma unroll
    for (int r = 0; r < 4; ++r) {
      const int n = base + r0 + r;
      if (n < nnodes) {
        ushort4 yv;
        yv.x = f2b(y0a[r] * 0.125f);        // /sqrt(C)
        yv.y = f2b(y1a[r][0] * 0.125f);
        yv.z = f2b(y1a[r][1] * 0.125f);
        yv.w = f2b(y1a[r][2] * 0.125f);
        *(ushort4*)(yqb + ((size_t)n * 64 + v) * 4) = yv;
        out[(size_t)n * 256 + v] = sc0a[r] * 0.0625f;   // /sqrt(C*A)
#pragma unroll
        for (int m = 0; m < 3; ++m)
          out[(size_t)n * 256 + 64 + v * 3 + m] = sc1a[r][m] * 0.0625f;
      }
    }
  }
}

// One node per WAVE; no barriers; bf16 gather; writes bf16 agg[n][512].
__global__ __launch_bounds__(256, 4) void k_agg(
    const unsigned short* __restrict__ yqb, const uint4* __restrict__ erec,
    const int* __restrict__ srcs, const int* __restrict__ offs,
    const float* __restrict__ Wf2, unsigned short* __restrict__ aggb, int nnodes) {
  const int tid = threadIdx.x;
  const int u = tid & 63;
  const int wv = tid >> 6;
  const int n = blockIdx.x * 4 + wv;
  if (n >= nnodes) return;

  float wreg[32];
#pragma unroll
  for (int j = 0; j < 8; ++j)
#pragma unroll
    for (int q = 0; q < 4; ++q) wreg[j * 4 + q] = Wf2[j * 256 + q * 64 + u];

  float as0 = 0.f, as1 = 0.f;
  float av0[3] = {0.f, 0.f, 0.f};
  float av1[3] = {0.f, 0.f, 0.f};

  const int beg = offs[n], end = offs[n + 1];
#pragma unroll 4
  for (int i = beg; i < end; ++i) {
    const int src = srcs[i];
    const ushort4 yb = *(const ushort4*)(yqb + ((size_t)src * 64 + u) * 4);
    const uint4 hp = erec[(size_t)i * 2];
    const uint4 shu = erec[(size_t)i * 2 + 1];
    const float4 sh = make_float4(__uint_as_float(shu.x), __uint_as_float(shu.y),
                                  __uint_as_float(shu.z), __uint_as_float(shu.w));
    const float hv[8] = {blo(hp.x), bhi(hp.x), blo(hp.y), bhi(hp.y),
                         blo(hp.z), bhi(hp.z), blo(hp.w), bhi(hp.w)};
    float wp[4] = {0.f, 0.f, 0.f, 0.f};
#pragma unroll
    for (int j = 0; j < 8; ++j)
#pragma unroll
      for (int q = 0; q < 4; ++q) wp[q] = fmaf(hv[j], wreg[j * 4 + q], wp[q]);
    const float y0 = b2f(yb.x), y1 = b2f(yb.y), y2 = b2f(yb.z), y3 = b2f(yb.w);
    const float dot3 = y1 * sh.y + y2 * sh.z + y3 * sh.w;
    as0 = fmaf(wp[0] * y0, sh.x, as0);
    as1 = fmaf(wp[3], dot3, as1);
    const float t2 = wp[1] * y0;
    av0[0] = fmaf(t2, sh.y, av0[0]);
    av0[1] = fmaf(t2, sh.z, av0[1]);
    av0[2] = fmaf(t2, sh.w, av0[2]);
    const float t3 = wp[2] * sh.x;
    av1[0] = fmaf(t3, y1, av1[0]);
    av1[1] = fmaf(t3, y2, av1[1]);
    av1[2] = fmaf(t3, y3, av1[2]);
  }

  unsigned short* ap = aggb + (size_t)n * 512;
  ap[u] = f2b(as0);
  ap[64 + u] = f2b(as1 * 0.57735026918962576f);  // /sqrt(3)
#pragma unroll
  for (int m = 0; m < 3; ++m) {
    ap[128 + m * 64 + u] = f2b(av0[m]);
    ap[320 + m * 64 + u] = f2b(av1[m]);
  }
}

// 16 nodes/block (4 per wave); bf16 agg unpacked into per-wave LDS f32 slice;
// packed row-pair weights; bounded unroll (anti-spill, round-3 lesson).
__global__ __launch_bounds__(256, 4) void k_lin2(
    const unsigned short* __restrict__ aggb, const unsigned* __restrict__ wpk2a,
    const unsigned* __restrict__ wpk2b, float* __restrict__ out, int nnodes) {
  __shared__ float s_x[4][4][512];  // 32 KB
  const int tid = threadIdx.x;
  const int u = tid & 63;
  const int wv = tid >> 6;
  const int nb = blockIdx.x * 16 + wv * 4;

#pragma unroll
  for (int r = 0; r < 4; ++r) {
    const int n = nb + r;
    if (n < nnodes) {
      const uint4 aw = *(const uint4*)(aggb + (size_t)n * 512 + u * 8);
      float4* dst = (float4*)&s_x[wv][r][u * 8];
      dst[0] = make_float4(blo(aw.x), bhi(aw.x), blo(aw.y), bhi(aw.y));
      dst[1] = make_float4(blo(aw.z), bhi(aw.z), blo(aw.w), bhi(aw.w));
    }
  }
  // per-wave private LDS slice: same-wave RAW only, no barrier needed.

  float o0[4] = {0.f, 0.f, 0.f, 0.f};
  float o1[4][3] = {};

#pragma unroll 2
  for (int up = 0; up < 64; ++up) {
    const unsigned qa = wpk2a[up * 64 + u];
    const unsigned qb = wpk2b[up * 64 + u];
    const float w20a = blo(qa), w20b = bhi(qa);
    const float w21a = blo(qb), w21b = bhi(qb);
#pragma unroll
    for (int r = 0; r < 4; ++r) {
      o0[r] = fmaf(s_x[wv][r][up], w20a, o0[r]);
      o0[r] = fmaf(s_x[wv][r][64 + up], w20b, o0[r]);
#pragma unroll
      for (int m = 0; m < 3; ++m) {
        o1[r][m] = fmaf(s_x[wv][r][128 + m * 64 + up], w21a, o1[r][m]);
        o1[r][m] = fmaf(s_x[wv][r][320 + m * 64 + up], w21b, o1[r][m]);
      }
    }
  }

  const float scl = 1.f / 64.f;  // 1/sqrt(32) * 1/sqrt(128)
#pragma unroll
  for (int r = 0; r < 4; ++r) {
    const int n = nb + r;
    if (n < nnodes) {
      out[(size_t)n * 256 + u] += o0[r] * scl;
#pragma unroll
      for (int m = 0; m < 3; ++m)
        out[(size_t)n * 256 + 64 + u * 3 + m] += o1[r][m] * scl;
    }
  }
}

extern "C" void kernel_launch(void* const* d_in, const int* in_sizes, int n_in,
                              void* d_out, int out_size, void* d_ws, size_t ws_size,
                              hipStream_t stream) {
  const float* nf = (const float*)d_in[0];
  const float* na = (const float*)d_in[1];
  const float* ea = (const float*)d_in[2];
  const float* ee = (const float*)d_in[3];
  const int* ei = (const int*)d_in[4];
  const float* W10 = (const float*)d_in[5];
  const float* W11 = (const float*)d_in[6];
  const float* Wf1 = (const float*)d_in[7];
  const float* Wf2 = (const float*)d_in[8];
  const float* W20 = (const float*)d_in[9];
  const float* W21 = (const float*)d_in[10];
  const float* Ws0 = (const float*)d_in[11];
  const float* Ws1 = (const float*)d_in[12];
  float* out = (float*)d_out;

  const int N = in_sizes[1] / 4;  // node_attrs is N x 4
  const int E = in_sizes[2] / 4;  // edge_attrs is E x 4

  char* w = (char*)d_ws;
  auto carve = [&](size_t bytes) {
    char* p = w;
    w += (bytes + 255) & ~(size_t)255;
    return p;
  };
  unsigned short* yqb = (unsigned short*)carve((size_t)N * 256 * 2);   // 5.12 MB
  uint4* erec = (uint4*)carve((size_t)E * 32);                         // 10.24 MB
  unsigned short* aggb = (unsigned short*)carve((size_t)N * 512 * 2);  // 10.24 MB
  unsigned* wpk1 = (unsigned*)carve(4096 * 4);
  unsigned* wpks = (unsigned*)carve(16384 * 4);
  unsigned* wpk2a = (unsigned*)carve(4096 * 4);
  unsigned* wpk2b = (unsigned*)carve(4096 * 4);
  int* cnt = (int*)carve((size_t)N * sizeof(int));
  int* offs = (int*)carve((size_t)(N + 1) * sizeof(int));
  int* cur = (int*)carve((size_t)N * sizeof(int));
  int* srcs = (int*)carve((size_t)E * sizeof(int));                    // 1.28 MB

  hipMemsetAsync(cnt, 0, (size_t)N * sizeof(int), stream);
  k_pack<<<(4096 + 16384 + 8192 + 255) / 256, 256, 0, stream>>>(
      W10, W11, Ws0, Ws1, W20, W21, wpk1, wpks, wpk2a, wpk2b);
  const int egrid = (E + 255) / 256;
  k_hist<<<egrid, 256, 0, stream>>>(ei, cnt, E);
  k_scan<<<1, 1024, 0, stream>>>(cnt, offs, cur, N, E);
  k_build<<<egrid, 256, 0, stream>>>(ei, ee, ea, Wf1, cur, srcs, erec, E);
  const int ngroups = (N + 15) / 16;
  const int npgrid = (ngroups < 256) ? ngroups : 256;
  k_node_pre<<<npgrid, 256, 0, stream>>>(nf, na, wpk1, wpks, yqb, out, N);
  k_agg<<<(N + 3) / 4, 256, 0, stream>>>(yqb, erec, srcs, offs, Wf2, aggb, N);
  k_lin2<<<(N + 15) / 16, 256, 0, stream>>>(aggb, wpk2a, wpk2b, out, N);
}

// Round 9
// 299.062 us; speedup vs baseline: 1.1234x; 1.0413x over previous
//
#include <hip/hip_runtime.h>

// InteractionBlock: N=10000, E=320000, C=64, A=4, NB=8, H=8.
// Pipeline:
//   k_pack     : bf16-pair pack of (W10,W11),(Ws0,Ws1),(W20 row-pairs),(W21 row-pairs)
//   memset cnt -> k_hist -> k_scan (2-barrier shuffle scan)
//   k_build    : CSR scatter + edge MLP; writes erec[p] = {uint4 bf16 h[8], f32 sh[4]}
//   k_node_pre : 1024 thr (16 waves, 4/SIMD); weights in LDS (80KB) + bf16 node
//                features (32KB); 64 nodes/block; yqb bf16 -> ws, sc f32 -> out
//   k_agg      : one node per WAVE, no barriers; Wf2 in regs; bf16 gather;
//                writes bf16 agg[n][512]
//   k_lin2     : 16 nodes/block (4/wave), agg unpacked to LDS f32, packed weights

__device__ __forceinline__ unsigned short f2b(float f) {
  unsigned u = __float_as_uint(f);
  return (unsigned short)((u + 0x7FFFu + ((u >> 16) & 1u)) >> 16);  // RNE
}
__device__ __forceinline__ unsigned packb(float a, float b) {
  return (unsigned)f2b(a) | ((unsigned)f2b(b) << 16);
}
__device__ __forceinline__ float blo(unsigned p) { return __uint_as_float(p << 16); }
__device__ __forceinline__ float bhi(unsigned p) { return __uint_as_float(p & 0xFFFF0000u); }
__device__ __forceinline__ float b2f(unsigned short h) {
  return __uint_as_float((unsigned)h << 16);
}

__global__ __launch_bounds__(256) void k_pack(
    const float* __restrict__ W10, const float* __restrict__ W11,
    const float* __restrict__ Ws0, const float* __restrict__ Ws1,
    const float* __restrict__ W20, const float* __restrict__ W21,
    unsigned* __restrict__ wpk1, unsigned* __restrict__ wpks,
    unsigned* __restrict__ wpk2a, unsigned* __restrict__ wpk2b) {
  int i = blockIdx.x * 256 + threadIdx.x;
  if (i < 4096) wpk1[i] = packb(W10[i], W11[i]);
  else if (i < 4096 + 16384) {
    int j = i - 4096;
    wpks[j] = packb(Ws0[j], Ws1[j]);
  } else if (i < 4096 + 16384 + 4096) {
    int j = i - (4096 + 16384);  // j = up*64+v, up<64
    wpk2a[j] = packb(W20[j], W20[4096 + j]);
  } else if (i < 4096 + 16384 + 8192) {
    int j = i - (4096 + 16384 + 4096);
    wpk2b[j] = packb(W21[j], W21[4096 + j]);
  }
}

__global__ __launch_bounds__(256) void k_hist(const int* __restrict__ ei,
                                              int* __restrict__ cnt, int nedges) {
  int e = blockIdx.x * 256 + threadIdx.x;
  if (e < nedges) atomicAdd(&cnt[ei[e]], 1);  // row 0 = dst
}

__global__ __launch_bounds__(1024) void k_scan(const int* __restrict__ cnt,
                                               int* __restrict__ offs,
                                               int* __restrict__ cur,
                                               int nnodes, int nedges) {
  __shared__ int s_wtot[16], s_wpre[16];
  const int tid = threadIdx.x;
  const int lane = tid & 63;
  const int w = tid >> 6;
  int vals[16];
  int tot = 0;
  const int start = tid * 16;
#pragma unroll
  for (int k = 0; k < 16; ++k) {
    int i = start + k;
    int c = (i < nnodes) ? cnt[i] : 0;
    vals[k] = c;
    tot += c;
  }
  int incl = tot;
#pragma unroll
  for (int off = 1; off < 64; off <<= 1) {
    int v = __shfl_up(incl, off, 64);
    if (lane >= off) incl += v;
  }
  if (lane == 63) s_wtot[w] = incl;
  __syncthreads();
  if (tid == 0) {
    int run = 0;
#pragma unroll
    for (int i = 0; i < 16; ++i) { s_wpre[i] = run; run += s_wtot[i]; }
  }
  __syncthreads();
  int run = s_wpre[w] + (incl - tot);
#pragma unroll
  for (int k = 0; k < 16; ++k) {
    int i = start + k;
    if (i < nnodes) {
      offs[i] = run;
      cur[i] = run;
      run += vals[k];
    }
  }
  if (tid == 0) offs[nnodes] = nedges;
}

// scatter + edge-MLP fused; one interleaved 32B record per edge.
__global__ __launch_bounds__(256) void k_build(
    const int* __restrict__ ei, const float* __restrict__ ee,
    const float* __restrict__ ea, const float* __restrict__ Wf1,
    int* __restrict__ cur, int* __restrict__ srcs,
    uint4* __restrict__ erec, int nedges) {
  __shared__ float s_w[64];
  const int tid = threadIdx.x;
  if (tid < 64) s_w[tid] = Wf1[tid];
  __syncthreads();
  int e = blockIdx.x * 256 + tid;
  if (e >= nedges) return;
  const int d = ei[e];
  const int s = ei[nedges + e];
  const int p = atomicAdd(&cur[d], 1);
  srcs[p] = s;
  const float4 a = *(const float4*)(ee + (size_t)e * 8);
  const float4 b = *(const float4*)(ee + (size_t)e * 8 + 4);
  float r[8];
  const float is8 = 0.35355339059327379f;  // 1/sqrt(8)
#pragma unroll
  for (int j = 0; j < 8; ++j) {
    float dd = a.x * s_w[0 * 8 + j] + a.y * s_w[1 * 8 + j] + a.z * s_w[2 * 8 + j] +
               a.w * s_w[3 * 8 + j] + b.x * s_w[4 * 8 + j] + b.y * s_w[5 * 8 + j] +
               b.z * s_w[6 * 8 + j] + b.w * s_w[7 * 8 + j];
    dd *= is8;                                        // /sqrt(NB)
    float sp = fmaxf(dd, 0.f) + log1pf(__expf(-fabsf(dd)));
    r[j] = (sp - 0.69314718055994531f) * is8;         // -ln2, fold /sqrt(H)
  }
  const float4 sh = *(const float4*)(ea + (size_t)e * 4);  // sh0, sh1
  erec[(size_t)p * 2] = make_uint4(packb(r[0], r[1]), packb(r[2], r[3]),
                                   packb(r[4], r[5]), packb(r[6], r[7]));
  erec[(size_t)p * 2 + 1] =
      make_uint4(__float_as_uint(sh.x), __float_as_uint(sh.y),
                 __float_as_uint(sh.z), __float_as_uint(sh.w));
}

// 1024 threads = 16 waves (4/SIMD for latency hiding); 64 nodes per block.
// Weights in LDS (80KB packed bf16-pairs) + node features bf16 (32KB).
// Lane = output column v; wave wv handles nodes base+wv*4 .. +3.
__global__ __launch_bounds__(1024) void k_node_pre(
    const float* __restrict__ nf, const float* __restrict__ na,
    const unsigned* __restrict__ wpk1, const unsigned* __restrict__ wpks,
    unsigned short* __restrict__ yqb, float* __restrict__ out, int nnodes) {
  __shared__ unsigned s_w1[4096];          // 16 KB: (W10,W11) packed, [u*64+v]
  __shared__ unsigned s_ws[16384];         // 64 KB: (Ws0,Ws1) packed, [(u*4+a)*64+v]
  __shared__ unsigned short s_nfb[64][256]; // 32 KB: node features bf16
  __shared__ float s_na[64][4];            // 1 KB
  const int tid = threadIdx.x;
  const int lane = tid & 63;
  const int wv = tid >> 6;

  for (int i = tid; i < 4096; i += 1024) s_w1[i] = wpk1[i];
  for (int i = tid; i < 16384; i += 1024) s_ws[i] = wpks[i];

  const int ngroups = (nnodes + 63) / 64;
  for (int g = blockIdx.x; g < ngroups; g += gridDim.x) {
    const int base = g * 64;
    __syncthreads();  // weight staging (first iter) + s_nfb reuse (later iters)
    for (int i = tid; i < 64 * 256; i += 1024) {
      int r = i >> 8, c = i & 255;
      int n = base + r;
      s_nfb[r][c] = (n < nnodes) ? f2b(nf[(size_t)n * 256 + c]) : (unsigned short)0;
    }
    if (tid < 256) {
      int r = tid >> 2, c = tid & 3;
      int n = base + r;
      s_na[r][c] = (n < nnodes) ? na[(size_t)n * 4 + c] : 0.f;
    }
    __syncthreads();

    const int r0 = wv * 4;
    const int v = lane;
    float y0a[4] = {0.f, 0.f, 0.f, 0.f};
    float y1a[4][3] = {};
    float sc0a[4] = {0.f, 0.f, 0.f, 0.f};
    float sc1a[4][3] = {};

#pragma unroll 2
    for (int u = 0; u < 64; ++u) {
      float x0r[4], x1r[4][3];
#pragma unroll
      for (int r = 0; r < 4; ++r) {
        x0r[r] = b2f(s_nfb[r0 + r][u]);
#pragma unroll
        for (int m = 0; m < 3; ++m) x1r[r][m] = b2f(s_nfb[r0 + r][64 + u * 3 + m]);
      }
      const unsigned q1 = s_w1[u * 64 + v];
      const float w0 = blo(q1);
      const float w1 = bhi(q1);
#pragma unroll
      for (int r = 0; r < 4; ++r) {
        y0a[r] = fmaf(x0r[r], w0, y0a[r]);
#pragma unroll
        for (int m = 0; m < 3; ++m) y1a[r][m] = fmaf(x1r[r][m], w1, y1a[r][m]);
      }
#pragma unroll
      for (int a = 0; a < 4; ++a) {
        const unsigned qs = s_ws[(u * 4 + a) * 64 + v];
        const float ws0 = blo(qs);
        const float ws1 = bhi(qs);
#pragma unroll
        for (int r = 0; r < 4; ++r) {
          const float nav = s_na[r0 + r][a];
          sc0a[r] = fmaf(x0r[r] * nav, ws0, sc0a[r]);
          const float t = nav * ws1;
#pragma unroll
          for (int m = 0; m < 3; ++m)
            sc1a[r][m] = fmaf(x1r[r][m], t, sc1a[r][m]);
        }
      }
    }

#pragma unroll
    for (int r = 0; r < 4; ++r) {
      const int n = base + r0 + r;
      if (n < nnodes) {
        ushort4 yv;
        yv.x = f2b(y0a[r] * 0.125f);        // /sqrt(C)
        yv.y = f2b(y1a[r][0] * 0.125f);
        yv.z = f2b(y1a[r][1] * 0.125f);
        yv.w = f2b(y1a[r][2] * 0.125f);
        *(ushort4*)(yqb + ((size_t)n * 64 + v) * 4) = yv;
        out[(size_t)n * 256 + v] = sc0a[r] * 0.0625f;   // /sqrt(C*A)
#pragma unroll
        for (int m = 0; m < 3; ++m)
          out[(size_t)n * 256 + 64 + v * 3 + m] = sc1a[r][m] * 0.0625f;
      }
    }
  }
}

// One node per WAVE; no barriers; bf16 gather; writes bf16 agg[n][512].
__global__ __launch_bounds__(256, 4) void k_agg(
    const unsigned short* __restrict__ yqb, const uint4* __restrict__ erec,
    const int* __restrict__ srcs, const int* __restrict__ offs,
    const float* __restrict__ Wf2, unsigned short* __restrict__ aggb, int nnodes) {
  const int tid = threadIdx.x;
  const int u = tid & 63;
  const int wv = tid >> 6;
  const int n = blockIdx.x * 4 + wv;
  if (n >= nnodes) return;

  float wreg[32];
#pragma unroll
  for (int j = 0; j < 8; ++j)
#pragma unroll
    for (int q = 0; q < 4; ++q) wreg[j * 4 + q] = Wf2[j * 256 + q * 64 + u];

  float as0 = 0.f, as1 = 0.f;
  float av0[3] = {0.f, 0.f, 0.f};
  float av1[3] = {0.f, 0.f, 0.f};

  const int beg = offs[n], end = offs[n + 1];
#pragma unroll 4
  for (int i = beg; i < end; ++i) {
    const int src = srcs[i];
    const ushort4 yb = *(const ushort4*)(yqb + ((size_t)src * 64 + u) * 4);
    const uint4 hp = erec[(size_t)i * 2];
    const uint4 shu = erec[(size_t)i * 2 + 1];
    const float4 sh = make_float4(__uint_as_float(shu.x), __uint_as_float(shu.y),
                                  __uint_as_float(shu.z), __uint_as_float(shu.w));
    const float hv[8] = {blo(hp.x), bhi(hp.x), blo(hp.y), bhi(hp.y),
                         blo(hp.z), bhi(hp.z), blo(hp.w), bhi(hp.w)};
    float wp[4] = {0.f, 0.f, 0.f, 0.f};
#pragma unroll
    for (int j = 0; j < 8; ++j)
#pragma unroll
      for (int q = 0; q < 4; ++q) wp[q] = fmaf(hv[j], wreg[j * 4 + q], wp[q]);
    const float y0 = b2f(yb.x), y1 = b2f(yb.y), y2 = b2f(yb.z), y3 = b2f(yb.w);
    const float dot3 = y1 * sh.y + y2 * sh.z + y3 * sh.w;
    as0 = fmaf(wp[0] * y0, sh.x, as0);
    as1 = fmaf(wp[3], dot3, as1);
    const float t2 = wp[1] * y0;
    av0[0] = fmaf(t2, sh.y, av0[0]);
    av0[1] = fmaf(t2, sh.z, av0[1]);
    av0[2] = fmaf(t2, sh.w, av0[2]);
    const float t3 = wp[2] * sh.x;
    av1[0] = fmaf(t3, y1, av1[0]);
    av1[1] = fmaf(t3, y2, av1[1]);
    av1[2] = fmaf(t3, y3, av1[2]);
  }

  unsigned short* ap = aggb + (size_t)n * 512;
  ap[u] = f2b(as0);
  ap[64 + u] = f2b(as1 * 0.57735026918962576f);  // /sqrt(3)
#pragma unroll
  for (int m = 0; m < 3; ++m) {
    ap[128 + m * 64 + u] = f2b(av0[m]);
    ap[320 + m * 64 + u] = f2b(av1[m]);
  }
}

// 16 nodes/block (4 per wave); bf16 agg unpacked into per-wave LDS f32 slice;
// packed row-pair weights; bounded unroll (anti-spill, round-3 lesson).
__global__ __launch_bounds__(256, 4) void k_lin2(
    const unsigned short* __restrict__ aggb, const unsigned* __restrict__ wpk2a,
    const unsigned* __restrict__ wpk2b, float* __restrict__ out, int nnodes) {
  __shared__ float s_x[4][4][512];  // 32 KB
  const int tid = threadIdx.x;
  const int u = tid & 63;
  const int wv = tid >> 6;
  const int nb = blockIdx.x * 16 + wv * 4;

#pragma unroll
  for (int r = 0; r < 4; ++r) {
    const int n = nb + r;
    if (n < nnodes) {
      const uint4 aw = *(const uint4*)(aggb + (size_t)n * 512 + u * 8);
      float4* dst = (float4*)&s_x[wv][r][u * 8];
      dst[0] = make_float4(blo(aw.x), bhi(aw.x), blo(aw.y), bhi(aw.y));
      dst[1] = make_float4(blo(aw.z), bhi(aw.z), blo(aw.w), bhi(aw.w));
    }
  }
  // per-wave private LDS slice: same-wave RAW only, no barrier needed.

  float o0[4] = {0.f, 0.f, 0.f, 0.f};
  float o1[4][3] = {};

#pragma unroll 2
  for (int up = 0; up < 64; ++up) {
    const unsigned qa = wpk2a[up * 64 + u];
    const unsigned qb = wpk2b[up * 64 + u];
    const float w20a = blo(qa), w20b = bhi(qa);
    const float w21a = blo(qb), w21b = bhi(qb);
#pragma unroll
    for (int r = 0; r < 4; ++r) {
      o0[r] = fmaf(s_x[wv][r][up], w20a, o0[r]);
      o0[r] = fmaf(s_x[wv][r][64 + up], w20b, o0[r]);
#pragma unroll
      for (int m = 0; m < 3; ++m) {
        o1[r][m] = fmaf(s_x[wv][r][128 + m * 64 + up], w21a, o1[r][m]);
        o1[r][m] = fmaf(s_x[wv][r][320 + m * 64 + up], w21b, o1[r][m]);
      }
    }
  }

  const float scl = 1.f / 64.f;  // 1/sqrt(32) * 1/sqrt(128)
#pragma unroll
  for (int r = 0; r < 4; ++r) {
    const int n = nb + r;
    if (n < nnodes) {
      out[(size_t)n * 256 + u] += o0[r] * scl;
#pragma unroll
      for (int m = 0; m < 3; ++m)
        out[(size_t)n * 256 + 64 + u * 3 + m] += o1[r][m] * scl;
    }
  }
}

extern "C" void kernel_launch(void* const* d_in, const int* in_sizes, int n_in,
                              void* d_out, int out_size, void* d_ws, size_t ws_size,
                              hipStream_t stream) {
  const float* nf = (const float*)d_in[0];
  const float* na = (const float*)d_in[1];
  const float* ea = (const float*)d_in[2];
  const float* ee = (const float*)d_in[3];
  const int* ei = (const int*)d_in[4];
  const float* W10 = (const float*)d_in[5];
  const float* W11 = (const float*)d_in[6];
  const float* Wf1 = (const float*)d_in[7];
  const float* Wf2 = (const float*)d_in[8];
  const float* W20 = (const float*)d_in[9];
  const float* W21 = (const float*)d_in[10];
  const float* Ws0 = (const float*)d_in[11];
  const float* Ws1 = (const float*)d_in[12];
  float* out = (float*)d_out;

  const int N = in_sizes[1] / 4;  // node_attrs is N x 4
  const int E = in_sizes[2] / 4;  // edge_attrs is E x 4

  char* w = (char*)d_ws;
  auto carve = [&](size_t bytes) {
    char* p = w;
    w += (bytes + 255) & ~(size_t)255;
    return p;
  };
  unsigned short* yqb = (unsigned short*)carve((size_t)N * 256 * 2);   // 5.12 MB
  uint4* erec = (uint4*)carve((size_t)E * 32);                         // 10.24 MB
  unsigned short* aggb = (unsigned short*)carve((size_t)N * 512 * 2);  // 10.24 MB
  unsigned* wpk1 = (unsigned*)carve(4096 * 4);
  unsigned* wpks = (unsigned*)carve(16384 * 4);
  unsigned* wpk2a = (unsigned*)carve(4096 * 4);
  unsigned* wpk2b = (unsigned*)carve(4096 * 4);
  int* cnt = (int*)carve((size_t)N * sizeof(int));
  int* offs = (int*)carve((size_t)(N + 1) * sizeof(int));
  int* cur = (int*)carve((size_t)N * sizeof(int));
  int* srcs = (int*)carve((size_t)E * sizeof(int));                    // 1.28 MB

  hipMemsetAsync(cnt, 0, (size_t)N * sizeof(int), stream);
  k_pack<<<(4096 + 16384 + 8192 + 255) / 256, 256, 0, stream>>>(
      W10, W11, Ws0, Ws1, W20, W21, wpk1, wpks, wpk2a, wpk2b);
  const int egrid = (E + 255) / 256;
  k_hist<<<egrid, 256, 0, stream>>>(ei, cnt, E);
  k_scan<<<1, 1024, 0, stream>>>(cnt, offs, cur, N, E);
  k_build<<<egrid, 256, 0, stream>>>(ei, ee, ea, Wf1, cur, srcs, erec, E);
  const int ngroups = (N + 63) / 64;  // 157
  k_node_pre<<<ngroups, 1024, 0, stream>>>(nf, na, wpk1, wpks, yqb, out, N);
  k_agg<<<(N + 3) / 4, 256, 0, stream>>>(yqb, erec, srcs, offs, Wf2, aggb, N);
  k_lin2<<<(N + 15) / 16, 256, 0, stream>>>(aggb, wpk2a, wpk2b, out, N);
}

// Round 10
// 287.678 us; speedup vs baseline: 1.1679x; 1.0396x over previous
//
#include <hip/hip_runtime.h>

// InteractionBlock: N=10000, E=320000, C=64, A=4, NB=8, H=8.
// Pipeline:
//   k_pack     : bf16-pair pack of (W10,W11),(Ws0,Ws1 as uint2 a-pairs),
//                (W20 row-pairs),(W21 row-pairs)
//   memset cnt -> k_hist -> k_scan (2-barrier shuffle scan)
//   k_build    : CSR scatter + edge MLP; writes erec[p] = {uint4 bf16 h[8], f32 sh[4]}
//   k_node_pre : 1024 thr (16 waves); weights in LDS (80KB) + ushort4-packed bf16
//                node features (32KB); 7 LDS issues per u-iter (r9: was 21)
//   k_agg      : one node per WAVE, no barriers; Wf2 in regs; bf16 gather;
//                writes bf16 agg[n][512]
//   k_lin2     : 16 nodes/block (4/wave), agg + packed weights both in LDS

__device__ __forceinline__ unsigned short f2b(float f) {
  unsigned u = __float_as_uint(f);
  return (unsigned short)((u + 0x7FFFu + ((u >> 16) & 1u)) >> 16);  // RNE
}
__device__ __forceinline__ unsigned packb(float a, float b) {
  return (unsigned)f2b(a) | ((unsigned)f2b(b) << 16);
}
__device__ __forceinline__ float blo(unsigned p) { return __uint_as_float(p << 16); }
__device__ __forceinline__ float bhi(unsigned p) { return __uint_as_float(p & 0xFFFF0000u); }
__device__ __forceinline__ float b2f(unsigned short h) {
  return __uint_as_float((unsigned)h << 16);
}

__global__ __launch_bounds__(256) void k_pack(
    const float* __restrict__ W10, const float* __restrict__ W11,
    const float* __restrict__ Ws0, const float* __restrict__ Ws1,
    const float* __restrict__ W20, const float* __restrict__ W21,
    unsigned* __restrict__ wpk1, unsigned* __restrict__ wpks,
    unsigned* __restrict__ wpk2a, unsigned* __restrict__ wpk2b) {
  int i = blockIdx.x * 256 + threadIdx.x;
  if (i < 4096) wpk1[i] = packb(W10[i], W11[i]);
  else if (i < 4096 + 16384) {
    int j = i - 4096;                       // j = u*256 + a*64 + v
    int u = j >> 8, a = (j >> 6) & 3, v = j & 63;
    // uint2 a-pair layout: pair index (u*2 + a/2)*64 + v, component a&1
    wpks[((u * 2 + (a >> 1)) * 64 + v) * 2 + (a & 1)] = packb(Ws0[j], Ws1[j]);
  } else if (i < 4096 + 16384 + 4096) {
    int j = i - (4096 + 16384);  // j = up*64+v, up<64
    wpk2a[j] = packb(W20[j], W20[4096 + j]);
  } else if (i < 4096 + 16384 + 8192) {
    int j = i - (4096 + 16384 + 4096);
    wpk2b[j] = packb(W21[j], W21[4096 + j]);
  }
}

__global__ __launch_bounds__(256) void k_hist(const int* __restrict__ ei,
                                              int* __restrict__ cnt, int nedges) {
  int e = blockIdx.x * 256 + threadIdx.x;
  if (e < nedges) atomicAdd(&cnt[ei[e]], 1);  // row 0 = dst
}

__global__ __launch_bounds__(1024) void k_scan(const int* __restrict__ cnt,
                                               int* __restrict__ offs,
                                               int* __restrict__ cur,
                                               int nnodes, int nedges) {
  __shared__ int s_wtot[16], s_wpre[16];
  const int tid = threadIdx.x;
  const int lane = tid & 63;
  const int w = tid >> 6;
  int vals[16];
  int tot = 0;
  const int start = tid * 16;
#pragma unroll
  for (int k = 0; k < 16; ++k) {
    int i = start + k;
    int c = (i < nnodes) ? cnt[i] : 0;
    vals[k] = c;
    tot += c;
  }
  int incl = tot;
#pragma unroll
  for (int off = 1; off < 64; off <<= 1) {
    int v = __shfl_up(incl, off, 64);
    if (lane >= off) incl += v;
  }
  if (lane == 63) s_wtot[w] = incl;
  __syncthreads();
  if (tid == 0) {
    int run = 0;
#pragma unroll
    for (int i = 0; i < 16; ++i) { s_wpre[i] = run; run += s_wtot[i]; }
  }
  __syncthreads();
  int run = s_wpre[w] + (incl - tot);
#pragma unroll
  for (int k = 0; k < 16; ++k) {
    int i = start + k;
    if (i < nnodes) {
      offs[i] = run;
      cur[i] = run;
      run += vals[k];
    }
  }
  if (tid == 0) offs[nnodes] = nedges;
}

// scatter + edge-MLP fused; one interleaved 32B record per edge.
__global__ __launch_bounds__(256) void k_build(
    const int* __restrict__ ei, const float* __restrict__ ee,
    const float* __restrict__ ea, const float* __restrict__ Wf1,
    int* __restrict__ cur, int* __restrict__ srcs,
    uint4* __restrict__ erec, int nedges) {
  __shared__ float s_w[64];
  const int tid = threadIdx.x;
  if (tid < 64) s_w[tid] = Wf1[tid];
  __syncthreads();
  int e = blockIdx.x * 256 + tid;
  if (e >= nedges) return;
  const int d = ei[e];
  const int s = ei[nedges + e];
  const int p = atomicAdd(&cur[d], 1);
  srcs[p] = s;
  const float4 a = *(const float4*)(ee + (size_t)e * 8);
  const float4 b = *(const float4*)(ee + (size_t)e * 8 + 4);
  float r[8];
  const float is8 = 0.35355339059327379f;  // 1/sqrt(8)
#pragma unroll
  for (int j = 0; j < 8; ++j) {
    float dd = a.x * s_w[0 * 8 + j] + a.y * s_w[1 * 8 + j] + a.z * s_w[2 * 8 + j] +
               a.w * s_w[3 * 8 + j] + b.x * s_w[4 * 8 + j] + b.y * s_w[5 * 8 + j] +
               b.z * s_w[6 * 8 + j] + b.w * s_w[7 * 8 + j];
    dd *= is8;                                        // /sqrt(NB)
    float sp = fmaxf(dd, 0.f) + log1pf(__expf(-fabsf(dd)));
    r[j] = (sp - 0.69314718055994531f) * is8;         // -ln2, fold /sqrt(H)
  }
  const float4 sh = *(const float4*)(ea + (size_t)e * 4);  // sh0, sh1
  erec[(size_t)p * 2] = make_uint4(packb(r[0], r[1]), packb(r[2], r[3]),
                                   packb(r[4], r[5]), packb(r[6], r[7]));
  erec[(size_t)p * 2 + 1] =
      make_uint4(__float_as_uint(sh.x), __float_as_uint(sh.y),
                 __float_as_uint(sh.z), __float_as_uint(sh.w));
}

// 1024 threads = 16 waves; 64 nodes/block. Weights in LDS (80KB) + node
// features as ushort4 {x0, x1m0..2} (32KB). Per u-iter per wave:
// 4x ds_read_b64 (features) + 1x b32 (w1) + 2x b64 (ws pairs) = 7 LDS issues.
__global__ __launch_bounds__(1024) void k_node_pre(
    const float* __restrict__ nf, const float* __restrict__ na,
    const unsigned* __restrict__ wpk1, const unsigned* __restrict__ wpks,
    unsigned short* __restrict__ yqb, float* __restrict__ out, int nnodes) {
  __shared__ unsigned s_w1[4096];    // 16 KB: (W10,W11) packed, [u*64+v]
  __shared__ uint2 s_ws2[8192];      // 64 KB: (Ws0,Ws1) a-pairs, [(u*2+a2)*64+v]
  __shared__ ushort4 s_nfb[64][64];  // 32 KB: [r][u] = bf16 {x0, x1m0,1,2}
  __shared__ float s_na[64][4];      // 1 KB
  const int tid = threadIdx.x;
  const int lane = tid & 63;
  const int wv = tid >> 6;

  for (int i = tid; i < 4096; i += 1024) s_w1[i] = wpk1[i];
  {
    const uint2* wsrc = (const uint2*)wpks;
    for (int i = tid; i < 8192; i += 1024) s_ws2[i] = wsrc[i];
  }

  const int ngroups = (nnodes + 63) / 64;
  for (int g = blockIdx.x; g < ngroups; g += gridDim.x) {
    const int base = g * 64;
    __syncthreads();  // weight staging (first iter) + s_nfb reuse (later iters)
    for (int i = tid; i < 64 * 64; i += 1024) {
      int r = i >> 6, u = i & 63;
      int n = base + r;
      ushort4 t = make_ushort4(0, 0, 0, 0);
      if (n < nnodes) {
        const float* row = nf + (size_t)n * 256;
        t.x = f2b(row[u]);
        t.y = f2b(row[64 + u * 3]);
        t.z = f2b(row[64 + u * 3 + 1]);
        t.w = f2b(row[64 + u * 3 + 2]);
      }
      s_nfb[r][u] = t;
    }
    if (tid < 256) {
      int r = tid >> 2, c = tid & 3;
      int n = base + r;
      s_na[r][c] = (n < nnodes) ? na[(size_t)n * 4 + c] : 0.f;
    }
    __syncthreads();

    const int r0 = wv * 4;
    const int v = lane;
    float nav[4][4];
#pragma unroll
    for (int r = 0; r < 4; ++r)
#pragma unroll
      for (int a = 0; a < 4; ++a) nav[r][a] = s_na[r0 + r][a];

    float y0a[4] = {0.f, 0.f, 0.f, 0.f};
    float y1a[4][3] = {};
    float sc0a[4] = {0.f, 0.f, 0.f, 0.f};
    float sc1a[4][3] = {};

#pragma unroll 2
    for (int u = 0; u < 64; ++u) {
      float x0r[4], x1r[4][3];
#pragma unroll
      for (int r = 0; r < 4; ++r) {
        const ushort4 xv = s_nfb[r0 + r][u];
        x0r[r] = b2f(xv.x);
        x1r[r][0] = b2f(xv.y);
        x1r[r][1] = b2f(xv.z);
        x1r[r][2] = b2f(xv.w);
      }
      const unsigned q1 = s_w1[u * 64 + v];
      const float w0 = blo(q1);
      const float w1 = bhi(q1);
#pragma unroll
      for (int r = 0; r < 4; ++r) {
        y0a[r] = fmaf(x0r[r], w0, y0a[r]);
#pragma unroll
        for (int m = 0; m < 3; ++m) y1a[r][m] = fmaf(x1r[r][m], w1, y1a[r][m]);
      }
#pragma unroll
      for (int a2 = 0; a2 < 2; ++a2) {
        const uint2 q = s_ws2[(u * 2 + a2) * 64 + v];
#pragma unroll
        for (int half = 0; half < 2; ++half) {
          const unsigned qq = half ? q.y : q.x;
          const int a = a2 * 2 + half;
          const float ws0 = blo(qq);
          const float ws1 = bhi(qq);
#pragma unroll
          for (int r = 0; r < 4; ++r) {
            sc0a[r] = fmaf(x0r[r] * nav[r][a], ws0, sc0a[r]);
            const float t = nav[r][a] * ws1;
#pragma unroll
            for (int m = 0; m < 3; ++m)
              sc1a[r][m] = fmaf(x1r[r][m], t, sc1a[r][m]);
          }
        }
      }
    }

#pragma unroll
    for (int r = 0; r < 4; ++r) {
      const int n = base + r0 + r;
      if (n < nnodes) {
        ushort4 yv;
        yv.x = f2b(y0a[r] * 0.125f);        // /sqrt(C)
        yv.y = f2b(y1a[r][0] * 0.125f);
        yv.z = f2b(y1a[r][1] * 0.125f);
        yv.w = f2b(y1a[r][2] * 0.125f);
        *(ushort4*)(yqb + ((size_t)n * 64 + v) * 4) = yv;
        out[(size_t)n * 256 + v] = sc0a[r] * 0.0625f;   // /sqrt(C*A)
#pragma unroll
        for (int m = 0; m < 3; ++m)
          out[(size_t)n * 256 + 64 + v * 3 + m] = sc1a[r][m] * 0.0625f;
      }
    }
  }
}

// One node per WAVE; no barriers; bf16 gather; writes bf16 agg[n][512].
__global__ __launch_bounds__(256, 4) void k_agg(
    const unsigned short* __restrict__ yqb, const uint4* __restrict__ erec,
    const int* __restrict__ srcs, const int* __restrict__ offs,
    const float* __restrict__ Wf2, unsigned short* __restrict__ aggb, int nnodes) {
  const int tid = threadIdx.x;
  const int u = tid & 63;
  const int wv = tid >> 6;
  const int n = blockIdx.x * 4 + wv;
  if (n >= nnodes) return;

  float wreg[32];
#pragma unroll
  for (int j = 0; j < 8; ++j)
#pragma unroll
    for (int q = 0; q < 4; ++q) wreg[j * 4 + q] = Wf2[j * 256 + q * 64 + u];

  float as0 = 0.f, as1 = 0.f;
  float av0[3] = {0.f, 0.f, 0.f};
  float av1[3] = {0.f, 0.f, 0.f};

  const int beg = offs[n], end = offs[n + 1];
#pragma unroll 4
  for (int i = beg; i < end; ++i) {
    const int src = srcs[i];
    const ushort4 yb = *(const ushort4*)(yqb + ((size_t)src * 64 + u) * 4);
    const uint4 hp = erec[(size_t)i * 2];
    const uint4 shu = erec[(size_t)i * 2 + 1];
    const float4 sh = make_float4(__uint_as_float(shu.x), __uint_as_float(shu.y),
                                  __uint_as_float(shu.z), __uint_as_float(shu.w));
    const float hv[8] = {blo(hp.x), bhi(hp.x), blo(hp.y), bhi(hp.y),
                         blo(hp.z), bhi(hp.z), blo(hp.w), bhi(hp.w)};
    float wp[4] = {0.f, 0.f, 0.f, 0.f};
#pragma unroll
    for (int j = 0; j < 8; ++j)
#pragma unroll
      for (int q = 0; q < 4; ++q) wp[q] = fmaf(hv[j], wreg[j * 4 + q], wp[q]);
    const float y0 = b2f(yb.x), y1 = b2f(yb.y), y2 = b2f(yb.z), y3 = b2f(yb.w);
    const float dot3 = y1 * sh.y + y2 * sh.z + y3 * sh.w;
    as0 = fmaf(wp[0] * y0, sh.x, as0);
    as1 = fmaf(wp[3], dot3, as1);
    const float t2 = wp[1] * y0;
    av0[0] = fmaf(t2, sh.y, av0[0]);
    av0[1] = fmaf(t2, sh.z, av0[1]);
    av0[2] = fmaf(t2, sh.w, av0[2]);
    const float t3 = wp[2] * sh.x;
    av1[0] = fmaf(t3, y1, av1[0]);
    av1[1] = fmaf(t3, y2, av1[1]);
    av1[2] = fmaf(t3, y3, av1[2]);
  }

  unsigned short* ap = aggb + (size_t)n * 512;
  ap[u] = f2b(as0);
  ap[64 + u] = f2b(as1 * 0.57735026918962576f);  // /sqrt(3)
#pragma unroll
  for (int m = 0; m < 3; ++m) {
    ap[128 + m * 64 + u] = f2b(av0[m]);
    ap[320 + m * 64 + u] = f2b(av1[m]);
  }
}

// 16 nodes/block (4 per wave); agg rows AND packed weights in LDS (64KB ->
// 2 blocks/CU); bounded unroll (anti-spill, round-3 lesson).
__global__ __launch_bounds__(256, 4) void k_lin2(
    const unsigned short* __restrict__ aggb, const unsigned* __restrict__ wpk2a,
    const unsigned* __restrict__ wpk2b, float* __restrict__ out, int nnodes) {
  __shared__ float s_x[4][4][512];  // 32 KB
  __shared__ unsigned s_w2[8192];   // 32 KB: wpk2a then wpk2b
  const int tid = threadIdx.x;
  const int u = tid & 63;
  const int wv = tid >> 6;
  const int nb = blockIdx.x * 16 + wv * 4;

  for (int i = tid; i < 4096; i += 256) {
    s_w2[i] = wpk2a[i];
    s_w2[4096 + i] = wpk2b[i];
  }
#pragma unroll
  for (int r = 0; r < 4; ++r) {
    const int n = nb + r;
    if (n < nnodes) {
      const uint4 aw = *(const uint4*)(aggb + (size_t)n * 512 + u * 8);
      float4* dst = (float4*)&s_x[wv][r][u * 8];
      dst[0] = make_float4(blo(aw.x), bhi(aw.x), blo(aw.y), bhi(aw.y));
      dst[1] = make_float4(blo(aw.z), bhi(aw.z), blo(aw.w), bhi(aw.w));
    }
  }
  __syncthreads();  // s_w2 staged by all threads, used by all waves

  float o0[4] = {0.f, 0.f, 0.f, 0.f};
  float o1[4][3] = {};

#pragma unroll 2
  for (int up = 0; up < 64; ++up) {
    const unsigned qa = s_w2[up * 64 + u];
    const unsigned qb = s_w2[4096 + up * 64 + u];
    const float w20a = blo(qa), w20b = bhi(qa);
    const float w21a = blo(qb), w21b = bhi(qb);
#pragma unroll
    for (int r = 0; r < 4; ++r) {
      o0[r] = fmaf(s_x[wv][r][up], w20a, o0[r]);
      o0[r] = fmaf(s_x[wv][r][64 + up], w20b, o0[r]);
#pragma unroll
      for (int m = 0; m < 3; ++m) {
        o1[r][m] = fmaf(s_x[wv][r][128 + m * 64 + up], w21a, o1[r][m]);
        o1[r][m] = fmaf(s_x[wv][r][320 + m * 64 + up], w21b, o1[r][m]);
      }
    }
  }

  const float scl = 1.f / 64.f;  // 1/sqrt(32) * 1/sqrt(128)
#pragma unroll
  for (int r = 0; r < 4; ++r) {
    const int n = nb + r;
    if (n < nnodes) {
      out[(size_t)n * 256 + u] += o0[r] * scl;
#pragma unroll
      for (int m = 0; m < 3; ++m)
        out[(size_t)n * 256 + 64 + u * 3 + m] += o1[r][m] * scl;
    }
  }
}

extern "C" void kernel_launch(void* const* d_in, const int* in_sizes, int n_in,
                              void* d_out, int out_size, void* d_ws, size_t ws_size,
                              hipStream_t stream) {
  const float* nf = (const float*)d_in[0];
  const float* na = (const float*)d_in[1];
  const float* ea = (const float*)d_in[2];
  const float* ee = (const float*)d_in[3];
  const int* ei = (const int*)d_in[4];
  const float* W10 = (const float*)d_in[5];
  const float* W11 = (const float*)d_in[6];
  const float* Wf1 = (const float*)d_in[7];
  const float* Wf2 = (const float*)d_in[8];
  const float* W20 = (const float*)d_in[9];
  const float* W21 = (const float*)d_in[10];
  const float* Ws0 = (const float*)d_in[11];
  const float* Ws1 = (const float*)d_in[12];
  float* out = (float*)d_out;

  const int N = in_sizes[1] / 4;  // node_attrs is N x 4
  const int E = in_sizes[2] / 4;  // edge_attrs is E x 4

  char* w = (char*)d_ws;
  auto carve = [&](size_t bytes) {
    char* p = w;
    w += (bytes + 255) & ~(size_t)255;
    return p;
  };
  unsigned short* yqb = (unsigned short*)carve((size_t)N * 256 * 2);   // 5.12 MB
  uint4* erec = (uint4*)carve((size_t)E * 32);                         // 10.24 MB
  unsigned short* aggb = (unsigned short*)carve((size_t)N * 512 * 2);  // 10.24 MB
  unsigned* wpk1 = (unsigned*)carve(4096 * 4);
  unsigned* wpks = (unsigned*)carve(16384 * 4);
  unsigned* wpk2a = (unsigned*)carve(4096 * 4);
  unsigned* wpk2b = (unsigned*)carve(4096 * 4);
  int* cnt = (int*)carve((size_t)N * sizeof(int));
  int* offs = (int*)carve((size_t)(N + 1) * sizeof(int));
  int* cur = (int*)carve((size_t)N * sizeof(int));
  int* srcs = (int*)carve((size_t)E * sizeof(int));                    // 1.28 MB

  hipMemsetAsync(cnt, 0, (size_t)N * sizeof(int), stream);
  k_pack<<<(4096 + 16384 + 8192 + 255) / 256, 256, 0, stream>>>(
      W10, W11, Ws0, Ws1, W20, W21, wpk1, wpks, wpk2a, wpk2b);
  const int egrid = (E + 255) / 256;
  k_hist<<<egrid, 256, 0, stream>>>(ei, cnt, E);
  k_scan<<<1, 1024, 0, stream>>>(cnt, offs, cur, N, E);
  k_build<<<egrid, 256, 0, stream>>>(ei, ee, ea, Wf1, cur, srcs, erec, E);
  const int ngroups = (N + 63) / 64;  // 157
  k_node_pre<<<ngroups, 1024, 0, stream>>>(nf, na, wpk1, wpks, yqb, out, N);
  k_agg<<<(N + 3) / 4, 256, 0, stream>>>(yqb, erec, srcs, offs, Wf2, aggb, N);
  k_lin2<<<(N + 15) / 16, 256, 0, stream>>>(aggb, wpk2a, wpk2b, out, N);
}

// Round 12
// 249.315 us; speedup vs baseline: 1.3476x; 1.1539x over previous
//
#include <hip/hip_runtime.h>

// InteractionBlock: N=10000, E=320000, C=64, A=4, NB=8, H=8.
// Pipeline:
//   k_pack     : build FRAGMENT-MAJOR bf16 B matrices for MFMA:
//                fb0=[Ws0(64x256)|W10] 64x320, fb1=[Ws1|W11], fw20/fw21 128x64
//   memset cnt -> k_hist -> k_scan -> k_build (CSR + edge MLP, unchanged)
//   k_node_pre : MFMA 16x16x32_bf16. Per 16-node tile x wave: X @ B -> 20 col-tiles;
//                ct<16: sc (combine with na per-lane), ct>=16: y -> yqb.
//   k_agg      : unchanged (one node/wave gather)
//   k_lin2     : MFMA: agg tiles @ W20/W21 frags, out += acc/64

typedef __attribute__((ext_vector_type(8))) short bf16x8;
typedef __attribute__((ext_vector_type(4))) float f32x4;

__device__ __forceinline__ unsigned short f2b(float f) {
  unsigned u = __float_as_uint(f);
  return (unsigned short)((u + 0x7FFFu + ((u >> 16) & 1u)) >> 16);  // RNE
}
__device__ __forceinline__ unsigned packb(float a, float b) {
  return (unsigned)f2b(a) | ((unsigned)f2b(b) << 16);
}
__device__ __forceinline__ float blo(unsigned p) { return __uint_as_float(p << 16); }
__device__ __forceinline__ float bhi(unsigned p) { return __uint_as_float(p & 0xFFFF0000u); }
__device__ __forceinline__ float b2f(unsigned short h) {
  return __uint_as_float((unsigned)h << 16);
}

// Fragment-major B packing. Frag (kt,ct): lane l, elem j -> B[k][c],
// k = kt*32 + (l>>4)*8 + j, c = ct*16 + (l&15).
__global__ __launch_bounds__(256) void k_pack(
    const float* __restrict__ W10, const float* __restrict__ W11,
    const float* __restrict__ Ws0, const float* __restrict__ Ws1,
    const float* __restrict__ W20, const float* __restrict__ W21,
    unsigned short* __restrict__ fb0, unsigned short* __restrict__ fb1,
    unsigned short* __restrict__ fw20, unsigned short* __restrict__ fw21) {
  int i = blockIdx.x * 256 + threadIdx.x;
  if (i < 20480) {  // fb0/fb1: kt(2) x ct(20) x 64 x 8
    int j = i & 7, lane = (i >> 3) & 63;
    int f = i >> 9;              // kt*20 + ct
    int ct = f % 20, kt = f / 20;
    int k = kt * 32 + ((lane >> 4) << 3) + j;
    int c = ct * 16 + (lane & 15);
    // Ws0[u][a][v] flat = u*256 + (a*64+v) = k*256 + c  (c<256)
    fb0[i] = f2b(c < 256 ? Ws0[k * 256 + c] : W10[k * 64 + (c - 256)]);
    fb1[i] = f2b(c < 256 ? Ws1[k * 256 + c] : W11[k * 64 + (c - 256)]);
  } else if (i < 20480 + 8192) {  // fw20/fw21: kt(4) x ct(4) x 64 x 8
    int t = i - 20480;
    int j = t & 7, lane = (t >> 3) & 63;
    int f = t >> 9;  // kt*4 + ct
    int ct = f & 3, kt = f >> 2;
    int k = kt * 32 + ((lane >> 4) << 3) + j;
    int c = ct * 16 + (lane & 15);
    fw20[t] = f2b(W20[k * 64 + c]);
    fw21[t] = f2b(W21[k * 64 + c]);
  }
}

__global__ __launch_bounds__(256) void k_hist(const int* __restrict__ ei,
                                              int* __restrict__ cnt, int nedges) {
  int e = blockIdx.x * 256 + threadIdx.x;
  if (e < nedges) atomicAdd(&cnt[ei[e]], 1);  // row 0 = dst
}

__global__ __launch_bounds__(1024) void k_scan(const int* __restrict__ cnt,
                                               int* __restrict__ offs,
                                               int* __restrict__ cur,
                                               int nnodes, int nedges) {
  __shared__ int s_wtot[16], s_wpre[16];
  const int tid = threadIdx.x;
  const int lane = tid & 63;
  const int w = tid >> 6;
  int vals[16];
  int tot = 0;
  const int start = tid * 16;
#pragma unroll
  for (int k = 0; k < 16; ++k) {
    int i = start + k;
    int c = (i < nnodes) ? cnt[i] : 0;
    vals[k] = c;
    tot += c;
  }
  int incl = tot;
#pragma unroll
  for (int off = 1; off < 64; off <<= 1) {
    int v = __shfl_up(incl, off, 64);
    if (lane >= off) incl += v;
  }
  if (lane == 63) s_wtot[w] = incl;
  __syncthreads();
  if (tid == 0) {
    int run = 0;
#pragma unroll
    for (int i = 0; i < 16; ++i) { s_wpre[i] = run; run += s_wtot[i]; }
  }
  __syncthreads();
  int run = s_wpre[w] + (incl - tot);
#pragma unroll
  for (int k = 0; k < 16; ++k) {
    int i = start + k;
    if (i < nnodes) {
      offs[i] = run;
      cur[i] = run;
      run += vals[k];
    }
  }
  if (tid == 0) offs[nnodes] = nedges;
}

// scatter + edge-MLP fused; one interleaved 32B record per edge.
__global__ __launch_bounds__(256) void k_build(
    const int* __restrict__ ei, const float* __restrict__ ee,
    const float* __restrict__ ea, const float* __restrict__ Wf1,
    int* __restrict__ cur, int* __restrict__ srcs,
    uint4* __restrict__ erec, int nedges) {
  __shared__ float s_w[64];
  const int tid = threadIdx.x;
  if (tid < 64) s_w[tid] = Wf1[tid];
  __syncthreads();
  int e = blockIdx.x * 256 + tid;
  if (e >= nedges) return;
  const int d = ei[e];
  const int s = ei[nedges + e];
  const int p = atomicAdd(&cur[d], 1);
  srcs[p] = s;
  const float4 a = *(const float4*)(ee + (size_t)e * 8);
  const float4 b = *(const float4*)(ee + (size_t)e * 8 + 4);
  float r[8];
  const float is8 = 0.35355339059327379f;  // 1/sqrt(8)
#pragma unroll
  for (int j = 0; j < 8; ++j) {
    float dd = a.x * s_w[0 * 8 + j] + a.y * s_w[1 * 8 + j] + a.z * s_w[2 * 8 + j] +
               a.w * s_w[3 * 8 + j] + b.x * s_w[4 * 8 + j] + b.y * s_w[5 * 8 + j] +
               b.z * s_w[6 * 8 + j] + b.w * s_w[7 * 8 + j];
    dd *= is8;                                        // /sqrt(NB)
    float sp = fmaxf(dd, 0.f) + log1pf(__expf(-fabsf(dd)));
    r[j] = (sp - 0.69314718055994531f) * is8;         // -ln2, fold /sqrt(H)
  }
  const float4 sh = *(const float4*)(ea + (size_t)e * 4);  // sh0, sh1
  erec[(size_t)p * 2] = make_uint4(packb(r[0], r[1]), packb(r[2], r[3]),
                                   packb(r[4], r[5]), packb(r[6], r[7]));
  erec[(size_t)p * 2 + 1] =
      make_uint4(__float_as_uint(sh.x), __float_as_uint(sh.y),
                 __float_as_uint(sh.z), __float_as_uint(sh.w));
}

// MFMA node precompute. 256 thr = 4 waves; 64 nodes/block; wave w -> 16-node
// tile. A = bf16 feature planes (XOR-swizzled 16B cols); B = frag-major LDS.
// 20 col-tiles: ct<16 -> sc (a=ct>>2, vt=ct&3, combine na in-lane);
// ct>=16 -> y (vt=ct-16), packed via per-wave LDS scratch into yqb ushort4.
__global__ __launch_bounds__(256) void k_node_pre(
    const float* __restrict__ nf, const float* __restrict__ na,
    const unsigned short* __restrict__ fb0, const unsigned short* __restrict__ fb1,
    unsigned short* __restrict__ yqb, float* __restrict__ out, int nnodes) {
  __shared__ __align__(16) unsigned short s_b0[20480];  // 40KB
  __shared__ __align__(16) unsigned short s_b1[20480];  // 40KB
  __shared__ __align__(16) unsigned short s_p[4][64][64];  // 32KB planes
  __shared__ __align__(16) float4 s_na4[64];            // 1KB
  __shared__ __align__(16) unsigned short s_y[4][16][64][4];  // 32KB
  const int tid = threadIdx.x;
  const int l = tid & 63;
  const int w = tid >> 6;
  const int base = blockIdx.x * 64;

  for (int i = tid; i < 2560; i += 256) {
    ((uint4*)s_b0)[i] = ((const uint4*)fb0)[i];
    ((uint4*)s_b1)[i] = ((const uint4*)fb1)[i];
  }
  for (int c = tid; c < 2048; c += 256) {  // plane chunks: p, node, u-octet
    int p = c >> 9, ln = (c >> 3) & 63, c8 = c & 7;
    int n = base + ln;
    unsigned short v[8];
    if (n < nnodes) {
      const float* row = nf + (size_t)n * 256;
      if (p == 0) {
#pragma unroll
        for (int j = 0; j < 8; ++j) v[j] = f2b(row[c8 * 8 + j]);
      } else {
        int m = p - 1;
#pragma unroll
        for (int j = 0; j < 8; ++j) v[j] = f2b(row[64 + (c8 * 8 + j) * 3 + m]);
      }
    } else {
#pragma unroll
      for (int j = 0; j < 8; ++j) v[j] = 0;
    }
    *(uint4*)&s_p[p][ln][(c8 ^ (ln & 7)) * 8] = *(uint4*)v;
  }
  {
    int ln = tid >> 2, a = tid & 3;
    int n = base + ln;
    ((float*)&s_na4[ln])[a] = (n < nnodes) ? na[(size_t)n * 4 + a] : 0.f;
  }
  __syncthreads();

  const int ln0 = w * 16;
  // resident A-frags: 4 planes x 2 k-tiles
  bf16x8 af[4][2];
  {
    const int ln = ln0 + (l & 15);
#pragma unroll
    for (int p = 0; p < 4; ++p)
#pragma unroll
      for (int kt = 0; kt < 2; ++kt) {
        int c8 = kt * 4 + (l >> 4);
        af[p][kt] = *(const bf16x8*)&s_p[p][ln][(c8 ^ (ln & 7)) * 8];
      }
  }
  float narf[4][4];
#pragma unroll
  for (int r = 0; r < 4; ++r) {
    float4 nv = s_na4[ln0 + (l >> 4) * 4 + r];
    narf[r][0] = nv.x; narf[r][1] = nv.y; narf[r][2] = nv.z; narf[r][3] = nv.w;
  }

#pragma unroll
  for (int q = 0; q < 4; ++q) {
    const unsigned short* sb = (q == 0) ? s_b0 : s_b1;
    float scr[4][4] = {};  // [vt][r]
#pragma unroll
    for (int ct = 0; ct < 20; ++ct) {
      f32x4 acc = {0.f, 0.f, 0.f, 0.f};
#pragma unroll
      for (int kt = 0; kt < 2; ++kt) {
        bf16x8 bf = *(const bf16x8*)&sb[((kt * 20 + ct) * 64 + l) * 8];
        acc = __builtin_amdgcn_mfma_f32_16x16x32_bf16(af[q][kt], bf, acc, 0, 0, 0);
      }
      if (ct < 16) {
        const int a = ct >> 2, vt = ct & 3;
#pragma unroll
        for (int r = 0; r < 4; ++r)
          scr[vt][r] = fmaf(narf[r][a], acc[r], scr[vt][r]);
      } else {
        const int vt = ct - 16;
#pragma unroll
        for (int r = 0; r < 4; ++r)
          s_y[w][(l >> 4) * 4 + r][vt * 16 + (l & 15)][q] = f2b(acc[r] * 0.125f);
      }
    }
#pragma unroll
    for (int vt = 0; vt < 4; ++vt)
#pragma unroll
      for (int r = 0; r < 4; ++r) {
        const int n = base + ln0 + (l >> 4) * 4 + r;
        if (n < nnodes) {
          const int v = vt * 16 + (l & 15);
          const float val = scr[vt][r] * 0.0625f;  // /sqrt(C*A)
          if (q == 0) out[(size_t)n * 256 + v] = val;
          else out[(size_t)n * 256 + 64 + v * 3 + (q - 1)] = val;
        }
      }
  }

  // assemble yqb ushort4 {y0, y1m0..2} (per-wave private s_y, same-wave RAW)
#pragma unroll
  for (int i = 0; i < 16; ++i) {
    int idx = i * 64 + l;
    int node = idx >> 6, v = idx & 63;
    int n = base + ln0 + node;
    if (n < nnodes) {
      ushort4 t = *(ushort4*)&s_y[w][node][v][0];
      *(ushort4*)(yqb + ((size_t)n * 64 + v) * 4) = t;
    }
  }
}

// One node per WAVE; no barriers; bf16 gather; writes bf16 agg[n][512].
__global__ __launch_bounds__(256, 4) void k_agg(
    const unsigned short* __restrict__ yqb, const uint4* __restrict__ erec,
    const int* __restrict__ srcs, const int* __restrict__ offs,
    const float* __restrict__ Wf2, unsigned short* __restrict__ aggb, int nnodes) {
  const int tid = threadIdx.x;
  const int u = tid & 63;
  const int wv = tid >> 6;
  const int n = blockIdx.x * 4 + wv;
  if (n >= nnodes) return;

  float wreg[32];
#pragma unroll
  for (int j = 0; j < 8; ++j)
#pragma unroll
    for (int q = 0; q < 4; ++q) wreg[j * 4 + q] = Wf2[j * 256 + q * 64 + u];

  float as0 = 0.f, as1 = 0.f;
  float av0[3] = {0.f, 0.f, 0.f};
  float av1[3] = {0.f, 0.f, 0.f};

  const int beg = offs[n], end = offs[n + 1];
#pragma unroll 4
  for (int i = beg; i < end; ++i) {
    const int src = srcs[i];
    const ushort4 yb = *(const ushort4*)(yqb + ((size_t)src * 64 + u) * 4);
    const uint4 hp = erec[(size_t)i * 2];
    const uint4 shu = erec[(size_t)i * 2 + 1];
    const float4 sh = make_float4(__uint_as_float(shu.x), __uint_as_float(shu.y),
                                  __uint_as_float(shu.z), __uint_as_float(shu.w));
    const float hv[8] = {blo(hp.x), bhi(hp.x), blo(hp.y), bhi(hp.y),
                         blo(hp.z), bhi(hp.z), blo(hp.w), bhi(hp.w)};
    float wp[4] = {0.f, 0.f, 0.f, 0.f};
#pragma unroll
    for (int j = 0; j < 8; ++j)
#pragma unroll
      for (int q = 0; q < 4; ++q) wp[q] = fmaf(hv[j], wreg[j * 4 + q], wp[q]);
    const float y0 = b2f(yb.x), y1 = b2f(yb.y), y2 = b2f(yb.z), y3 = b2f(yb.w);
    const float dot3 = y1 * sh.y + y2 * sh.z + y3 * sh.w;
    as0 = fmaf(wp[0] * y0, sh.x, as0);
    as1 = fmaf(wp[3], dot3, as1);
    const float t2 = wp[1] * y0;
    av0[0] = fmaf(t2, sh.y, av0[0]);
    av0[1] = fmaf(t2, sh.z, av0[1]);
    av0[2] = fmaf(t2, sh.w, av0[2]);
    const float t3 = wp[2] * sh.x;
    av1[0] = fmaf(t3, y1, av1[0]);
    av1[1] = fmaf(t3, y2, av1[1]);
    av1[2] = fmaf(t3, y3, av1[2]);
  }

  unsigned short* ap = aggb + (size_t)n * 512;
  ap[u] = f2b(as0);
  ap[64 + u] = f2b(as1 * 0.57735026918962576f);  // /sqrt(3)
#pragma unroll
  for (int m = 0; m < 3; ++m) {
    ap[128 + m * 64 + u] = f2b(av0[m]);
    ap[320 + m * 64 + u] = f2b(av1[m]);
  }
}

// MFMA lin2: 256 thr = 4 waves, 64 nodes/block. A-frags direct from aggb
// (global, L2-hot); B = fw20/fw21 frags in LDS. out += acc/64.
__global__ __launch_bounds__(256) void k_lin2(
    const unsigned short* __restrict__ aggb, const unsigned short* __restrict__ fw20,
    const unsigned short* __restrict__ fw21, float* __restrict__ out, int nnodes) {
  __shared__ __align__(16) unsigned short s_w[2][8192];  // 16KB each
  const int tid = threadIdx.x;
  const int l = tid & 63;
  const int w = tid >> 6;
  const int base = blockIdx.x * 64;

  for (int i = tid; i < 1024; i += 256) {
    ((uint4*)s_w[0])[i] = ((const uint4*)fw20)[i];
    ((uint4*)s_w[1])[i] = ((const uint4*)fw21)[i];
  }
  __syncthreads();

  const int ln0 = w * 16;
  int nrow = base + ln0 + (l & 15);
  if (nrow >= nnodes) nrow = nnodes - 1;  // clamp (stores guarded)
  const unsigned short* arow = aggb + (size_t)nrow * 512;

#pragma unroll
  for (int q = 0; q < 4; ++q) {
    bf16x8 af[4];
#pragma unroll
    for (int kt = 0; kt < 4; ++kt) {
      int k = kt * 32 + ((l >> 4) << 3);
      int off = (q == 0) ? k
                         : (k < 64 ? 128 + (q - 1) * 64 + k
                                   : 320 + (q - 1) * 64 + (k - 64));
      af[kt] = *(const bf16x8*)(arow + off);
    }
    const unsigned short* sw = (q == 0) ? s_w[0] : s_w[1];
#pragma unroll
    for (int ct = 0; ct < 4; ++ct) {
      f32x4 acc = {0.f, 0.f, 0.f, 0.f};
#pragma unroll
      for (int kt = 0; kt < 4; ++kt) {
        bf16x8 bf = *(const bf16x8*)&sw[((kt * 4 + ct) * 64 + l) * 8];
        acc = __builtin_amdgcn_mfma_f32_16x16x32_bf16(af[kt], bf, acc, 0, 0, 0);
      }
#pragma unroll
      for (int r = 0; r < 4; ++r) {
        const int n = base + ln0 + (l >> 4) * 4 + r;
        if (n < nnodes) {
          const int v = ct * 16 + (l & 15);
          const size_t o =
              (size_t)n * 256 + ((q == 0) ? v : 64 + v * 3 + (q - 1));
          out[o] += acc[r] * 0.015625f;  // 1/sqrt(32)/sqrt(128)
        }
      }
    }
  }
}

extern "C" void kernel_launch(void* const* d_in, const int* in_sizes, int n_in,
                              void* d_out, int out_size, void* d_ws, size_t ws_size,
                              hipStream_t stream) {
  const float* nf = (const float*)d_in[0];
  const float* na = (const float*)d_in[1];
  const float* ea = (const float*)d_in[2];
  const float* ee = (const float*)d_in[3];
  const int* ei = (const int*)d_in[4];
  const float* W10 = (const float*)d_in[5];
  const float* W11 = (const float*)d_in[6];
  const float* Wf1 = (const float*)d_in[7];
  const float* Wf2 = (const float*)d_in[8];
  const float* W20 = (const float*)d_in[9];
  const float* W21 = (const float*)d_in[10];
  const float* Ws0 = (const float*)d_in[11];
  const float* Ws1 = (const float*)d_in[12];
  float* out = (float*)d_out;

  const int N = in_sizes[1] / 4;  // node_attrs is N x 4
  const int E = in_sizes[2] / 4;  // edge_attrs is E x 4

  char* w = (char*)d_ws;
  auto carve = [&](size_t bytes) {
    char* p = w;
    w += (bytes + 255) & ~(size_t)255;
    return p;
  };
  unsigned short* yqb = (unsigned short*)carve((size_t)N * 256 * 2);   // 5.12 MB
  uint4* erec = (uint4*)carve((size_t)E * 32);                         // 10.24 MB
  unsigned short* aggb = (unsigned short*)carve((size_t)N * 512 * 2);  // 10.24 MB
  unsigned short* fb0 = (unsigned short*)carve(20480 * 2);
  unsigned short* fb1 = (unsigned short*)carve(20480 * 2);
  unsigned short* fw20 = (unsigned short*)carve(8192 * 2);
  unsigned short* fw21 = (unsigned short*)carve(8192 * 2);
  int* cnt = (int*)carve((size_t)N * sizeof(int));
  int* offs = (int*)carve((size_t)(N + 1) * sizeof(int));
  int* cur = (int*)carve((size_t)N * sizeof(int));
  int* srcs = (int*)carve((size_t)E * sizeof(int));                    // 1.28 MB

  hipMemsetAsync(cnt, 0, (size_t)N * sizeof(int), stream);
  k_pack<<<(20480 + 8192 + 255) / 256, 256, 0, stream>>>(
      W10, W11, Ws0, Ws1, W20, W21, fb0, fb1, fw20, fw21);
  const int egrid = (E + 255) / 256;
  k_hist<<<egrid, 256, 0, stream>>>(ei, cnt, E);
  k_scan<<<1, 1024, 0, stream>>>(cnt, offs, cur, N, E);
  k_build<<<egrid, 256, 0, stream>>>(ei, ee, ea, Wf1, cur, srcs, erec, E);
  const int ngrid = (N + 63) / 64;  // 157
  k_node_pre<<<ngrid, 256, 0, stream>>>(nf, na, fb0, fb1, yqb, out, N);
  k_agg<<<(N + 3) / 4, 256, 0, stream>>>(yqb, erec, srcs, offs, Wf2, aggb, N);
  k_lin2<<<ngrid, 256, 0, stream>>>(aggb, fw20, fw21, out, N);
}